// Round 5
// baseline (306.737 us; speedup 1.0000x reference)
//
#include <hip/hip_runtime.h>
#include <math.h>

#define DIMX   1024
#define SDN    1024
#define BATCHN 2
#define LSEQ   2048
#define BLROWS (BATCHN*LSEQ)
#define NCHUNK 64
#define LCHUNK (LSEQ/NCHUNK)
#define PI_F   3.14159265358979f

typedef unsigned short ushort_t;
typedef __bf16 bf16_t;
typedef bf16_t bf16x8 __attribute__((ext_vector_type(8)));
typedef float f32x4 __attribute__((ext_vector_type(4)));

__device__ __forceinline__ float softplusf_(float x) {
  return x > 20.0f ? x : log1pf(expf(x));
}

__device__ __forceinline__ ushort_t f2bf_rne(float f) {
  unsigned u = __float_as_uint(f);
  u = u + 0x7fffu + ((u >> 16) & 1u);
  return (ushort_t)(u >> 16);
}

__device__ __forceinline__ float bf2f(ushort_t u) {
  return __uint_as_float(((unsigned)u) << 16);
}

__device__ __forceinline__ float2 cfma2(float2 a, float2 v, float2 u) {
  float re = fmaf(a.x, v.x, fmaf(-a.y, v.y, u.x));
  float im = fmaf(a.x, v.y, fmaf(a.y, v.x, u.y));
  return make_float2(re, im);
}

__device__ __forceinline__ void gload_lds16(const ushort_t* g, ushort_t* l) {
  __builtin_amdgcn_global_load_lds(
      (const __attribute__((address_space(1))) void*)g,
      (__attribute__((address_space(3))) void*)l, 16, 0, 0);
}

// ---------------- fused weight/x conversion + bias concat ----------------
// blocks [0,4096): x -> xb; [4096,6144): W_psi; [6144,8192): W_phi;
// [8192,9216): W_bs; [9216,10240): W_ps; [10240,11264): W_btx;
// [11264,12288): W_ptx; [12288,14336): W_bth; [14336,14368): bias concat.
__global__ __launch_bounds__(256) void wcvt_kernel(
    const float* __restrict__ x,
    const float* __restrict__ Wpsi, const float* __restrict__ Wphi,
    const float* __restrict__ Wbs, const float* __restrict__ Wps,
    const float* __restrict__ Wbtx, const float* __restrict__ Wptx,
    const float* __restrict__ Wbth,
    const float* __restrict__ b_psi, const float* __restrict__ b_phi,
    const float* __restrict__ b_bs, const float* __restrict__ b_ps,
    const float* __restrict__ b_btx, const float* __restrict__ b_ptx,
    ushort_t* __restrict__ xb, ushort_t* __restrict__ wcat,
    ushort_t* __restrict__ wbthb, float* __restrict__ bcat) {
  int b = blockIdx.x;
  if (b >= 14336) {
    int n = (b - 14336) * 256 + threadIdx.x;  // 0..8191
    float v;
    if (n < 2048) v = b_psi[n];
    else if (n < 4096) v = b_phi[n - 2048];
    else if (n < 5120) v = b_bs[n - 4096];
    else if (n < 6144) v = b_ps[n - 5120];
    else if (n < 7168) v = b_btx[n - 6144];
    else v = b_ptx[n - 7168];
    bcat[n] = v;
    return;
  }
  const float* src; ushort_t* dst; int off;
  if (b < 4096)       { src = x;    dst = xb;               off = b; }
  else if (b < 6144)  { src = Wpsi; dst = wcat;             off = b - 4096; }
  else if (b < 8192)  { src = Wphi; dst = wcat + 2097152u;  off = b - 6144; }
  else if (b < 9216)  { src = Wbs;  dst = wcat + 4194304u;  off = b - 8192; }
  else if (b < 10240) { src = Wps;  dst = wcat + 5242880u;  off = b - 9216; }
  else if (b < 11264) { src = Wbtx; dst = wcat + 6291456u;  off = b - 10240; }
  else if (b < 12288) { src = Wptx; dst = wcat + 7340032u;  off = b - 11264; }
  else                { src = Wbth; dst = wbthb;            off = b - 12288; }
  int i = (off * 256 + threadIdx.x) * 4;
  float4 v = *(const float4*)(src + i);
  ushort4 o;
  o.x = f2bf_rne(v.x); o.y = f2bf_rne(v.y);
  o.z = f2bf_rne(v.z); o.w = f2bf_rne(v.w);
  *(ushort4*)(dst + i) = o;
}

// ---------------- coefficients: a = exp(lam*dt), A = a^LCHUNK ----------------
__global__ void coef_kernel(const float* __restrict__ omega,
                            const float* __restrict__ log_gamma,
                            const float* __restrict__ dt,
                            float2* __restrict__ a_out,
                            float2* __restrict__ A_out) {
  int s = blockIdx.x * blockDim.x + threadIdx.x;
  if (s >= SDN) return;
  double dtv = (double)dt[0];
  double dte = dtv > 20.0 ? dtv : log1p(exp(dtv));
  double gam = 0.0;
  if (s < SDN - SDN / 4) {  // band0 = indices [768,1023] (freqs strictly decreasing)
    double lg = (double)log_gamma[s];
    gam = lg > 20.0 ? lg : log1p(exp(lg));
  }
  double th = (double)omega[s] * dte;
  double r  = exp(-gam * dte);
  a_out[s] = make_float2((float)(r * cos(th)), (float)(r * sin(th)));
  double thl = th * (double)LCHUNK;
  double rl  = exp(-gam * dte * (double)LCHUNK);
  A_out[s] = make_float2((float)(rl * cos(thl)), (float)(rl * sin(thl)));
}

// ---------------- gate ----------------
__global__ __launch_bounds__(256) void gate_kernel(
    const float* __restrict__ x, const float* __restrict__ z,
    const float* __restrict__ Wg, const float* __restrict__ bg,
    const float* __restrict__ sg, float* __restrict__ gate) {
  int m = blockIdx.x * 4 + (threadIdx.x >> 6);
  int lane = threadIdx.x & 63;
  const float* xp = x + (size_t)m * DIMX;
  const float* zp = z + (size_t)m * DIMX;
  float dot = 0.f, sur = 0.f;
  for (int i = lane; i < DIMX; i += 64) {
    float xv = xp[i];
    dot = fmaf(xv, Wg[i], dot);
    sur += fabsf(xv - zp[i]);
  }
#pragma unroll
  for (int o = 32; o > 0; o >>= 1) {
    dot += __shfl_down(dot, o, 64);
    sur += __shfl_down(sur, o, 64);
  }
  if (lane == 0) {
    float gs = 1.f / (1.f + expf(-(dot + bg[0])));
    gate[m] = gs * (1.f + tanhf(sg[0]) * (sur * (1.f / DIMX)));
  }
}

// ---------------- bf16 MFMA GEMM (unchanged from R4 — verified) ----------------
template<int MODE>
__global__ __launch_bounds__(256, 2) void gemm_bf16(
    const ushort_t* __restrict__ Xb, const ushort_t* __restrict__ Wb,
    const float* __restrict__ bias, ushort_t* __restrict__ Cb) {
  __shared__ ushort_t As[2][4096];  // [buf][128 rows][32 k] (granule-rotated)
  __shared__ ushort_t Bs[2][4096];
  const int tid = threadIdx.x;
  const int w = tid >> 6, l = tid & 63;
  int bm, bn, ldx, ldw;
  const ushort_t *Xp, *Wp;
  if (MODE == 0) {
    int b = blockIdx.x;
    int xcd = b & 7, idx = b >> 3;
    int tx = ((xcd & 3) << 4) + (idx & 15);   // 0..63
    int ty = ((xcd >> 2) << 4) + (idx >> 4);  // 0..31
    bm = ty << 7; bn = tx << 7;
    ldx = 1024; ldw = 1024;
    Xp = Xb; Wp = Wb;
  } else {
    bm = blockIdx.y << 7; bn = blockIdx.x << 7;
    ldx = 2048; ldw = 2048;
    Xp = Xb + blockIdx.z * 1024;
    Wp = Wb + blockIdx.z * 1024;
  }
  const int wr = w >> 1, wc = w & 1;

  const int srow = tid >> 2;
  const int c8 = (((tid & 3) - (tid >> 3)) & 3) << 3;
  const ushort_t* ga0 = Xp + (size_t)(bm + srow) * ldx + c8;
  const ushort_t* ga1 = Xp + (size_t)(bm + 64 + srow) * ldx + c8;
  const ushort_t* gb0 = Wp + (size_t)(bn + srow) * ldw + c8;
  const ushort_t* gb1 = Wp + (size_t)(bn + 64 + srow) * ldw + c8;

  f32x4 acc[4][4] = {};
  const int nk = 32;

#define STAGE(buf, kt)                                   \
  do {                                                   \
    gload_lds16(ga0 + (kt), &As[buf][w * 512]);          \
    gload_lds16(ga1 + (kt), &As[buf][2048 + w * 512]);   \
    gload_lds16(gb0 + (kt), &Bs[buf][w * 512]);          \
    gload_lds16(gb1 + (kt), &Bs[buf][2048 + w * 512]);   \
  } while (0)

  STAGE(0, 0);
  __syncthreads();

  const int rl = l & 15, kh = l >> 4;
  const int chunkp = (kh + (rl >> 1)) & 3;
  for (int kt = 0; kt < nk; ++kt) {
    int cur = kt & 1;
    if (kt + 1 < nk) STAGE(cur ^ 1, (kt + 1) * 32);
    const uint4* Af = (const uint4*)As[cur];
    const uint4* Bf = (const uint4*)Bs[cur];
    bf16x8 a[4], b[4];
#pragma unroll
    for (int i = 0; i < 4; ++i)
      a[i] = __builtin_bit_cast(bf16x8, Af[(wr * 64 + i * 16 + rl) * 4 + chunkp]);
#pragma unroll
    for (int j = 0; j < 4; ++j)
      b[j] = __builtin_bit_cast(bf16x8, Bf[(wc * 64 + j * 16 + rl) * 4 + chunkp]);
#pragma unroll
    for (int i = 0; i < 4; ++i)
#pragma unroll
      for (int j = 0; j < 4; ++j)
        acc[i][j] = __builtin_amdgcn_mfma_f32_16x16x32_bf16(a[i], b[j], acc[i][j], 0, 0, 0);
    __syncthreads();
  }
#undef STAGE

#pragma unroll
  for (int i = 0; i < 4; ++i) {
    int mrow = bm + wr * 64 + i * 16 + (l >> 4) * 4;
#pragma unroll
    for (int j = 0; j < 4; ++j) {
      int ncol = bn + wc * 64 + j * 16 + (l & 15);
      if (MODE == 0) {
        float bv = bias[ncol];
#pragma unroll
        for (int r = 0; r < 4; ++r)
          Cb[(size_t)(mrow + r) * 8192 + ncol] = f2bf_rne(acc[i][j][r] + bv);
      } else {
        ushort_t* P = Cb + (size_t)blockIdx.z * (4096u * 1024u);
#pragma unroll
        for (int r = 0; r < 4; ++r)
          P[(size_t)(mrow + r) * 1024 + ncol] = f2bf_rne(acc[i][j][r]);
      }
    }
  }
}

// proj row layout (8192 bf16): [0:1024) psi_re | [1024:2048) psi_im |
// [2048:3072) phi_re | [3072:4096) phi_im | [4096..) bs | ps | btx | ptx

// ---------------- fused U computation (MODE 0 scout, MODE 1 true) ----------------
template<int MODE>
__device__ __forceinline__ float2 compute_u(
    int m, int s, const ushort_t* __restrict__ proj,
    const float* __restrict__ gate, const ushort_t* __restrict__ P0,
    const ushort_t* __restrict__ P1, const float* __restrict__ b_bth) {
  const ushort_t* pr = proj + ((size_t)m << 13);
  float g = gate[m];
  float blv, phl;
  if (MODE == 0) {
    blv = bf2f(pr[4096 + s]);
    phl = bf2f(pr[5120 + s]);
  } else {
    size_t idx = ((size_t)m << 10) + s;
    blv = bf2f(pr[6144 + s]) + bf2f(P0[idx]) + bf2f(P1[idx]) + b_bth[s];
    phl = bf2f(pr[7168 + s]);
  }
  float bv = softplusf_(blv);
  float ph = PI_F * tanhf(phl);
  float sph, cph;
  sincosf(ph, &sph, &cph);
  float br = bv * cph, bi = bv * sph;
  float pre = bf2f(pr[s]), pim = bf2f(pr[1024 + s]);
  return make_float2(g * (br * pre - bi * pim), g * (br * pim + bi * pre));
}

// ---------------- chunked parallel scan (U fused) ----------------
template<int MODE>
__global__ __launch_bounds__(256) void scan_stage1(
    const ushort_t* __restrict__ proj, const float* __restrict__ gate,
    const ushort_t* __restrict__ P0, const ushort_t* __restrict__ P1,
    const float* __restrict__ b_bth, const float2* __restrict__ a,
    float2* __restrict__ carry) {
  int s = blockIdx.x * 256 + threadIdx.x;
  int c = blockIdx.y, b = blockIdx.z;
  float2 av = a[s];
  float2 V = make_float2(0.f, 0.f);
  int m0 = b * LSEQ + c * LCHUNK;
#pragma unroll 2
  for (int t = 0; t < LCHUNK; ++t)
    V = cfma2(av, V, compute_u<MODE>(m0 + t, s, proj, gate, P0, P1, b_bth));
  carry[(size_t)(b * NCHUNK + c) * SDN + s] = V;
}

__global__ __launch_bounds__(256) void scan_stage2(
    const float2* __restrict__ carry, const float2* __restrict__ A,
    float2* __restrict__ prefix) {
  int s = blockIdx.x * 256 + threadIdx.x;
  int b = blockIdx.z;
  float2 Av = A[s];
  float2 P = make_float2(0.f, 0.f);
  for (int c = 0; c < NCHUNK; ++c) {
    size_t off = (size_t)(b * NCHUNK + c) * SDN + s;
    prefix[off] = P;
    P = cfma2(Av, P, carry[off]);
  }
}

template<int MODE>
__global__ __launch_bounds__(256) void scan_stage3(
    const ushort_t* __restrict__ proj, const float* __restrict__ gate,
    const ushort_t* __restrict__ P0, const ushort_t* __restrict__ P1,
    const float* __restrict__ b_bth, const float2* __restrict__ a,
    const float2* __restrict__ prefix, float2* __restrict__ Vout) {
  int s = blockIdx.x * 256 + threadIdx.x;
  int c = blockIdx.y, b = blockIdx.z;
  float2 av = a[s];
  float2 V = prefix[(size_t)(b * NCHUNK + c) * SDN + s];
  int m0 = b * LSEQ + c * LCHUNK;
  size_t base = (size_t)m0 * SDN + s;
#pragma unroll 2
  for (int t = 0; t < LCHUNK; ++t) {
    V = cfma2(av, V, compute_u<MODE>(m0 + t, s, proj, gate, P0, P1, b_bth));
    Vout[base + (size_t)t * SDN] = V;
  }
}

// ---------------- H_flat (bf16): shifted, RMS-normalized scout state ----------------
__global__ __launch_bounds__(256) void hflat_kernel(
    const float2* __restrict__ V, ushort_t* __restrict__ Hflat) {
  int m = blockIdx.x;
  int t = m & (LSEQ - 1);
  float2 v[4];
  float sum = 0.f;
#pragma unroll
  for (int i = 0; i < 4; ++i) {
    int s = threadIdx.x + i * 256;
    float2 vv = make_float2(0.f, 0.f);
    if (t > 0) vv = V[(size_t)(m - 1) * SDN + s];
    v[i] = vv;
    sum += vv.x * vv.x + vv.y * vv.y;
  }
  __shared__ float red[256];
  red[threadIdx.x] = sum;
  __syncthreads();
  for (int o = 128; o > 0; o >>= 1) {
    if (threadIdx.x < o) red[threadIdx.x] += red[threadIdx.x + o];
    __syncthreads();
  }
  float inv = 1.0f / sqrtf(red[0] * (1.f / SDN) + 1e-6f);
  ushort_t* hr = Hflat + ((size_t)m << 11);
#pragma unroll
  for (int i = 0; i < 4; ++i) {
    int s = threadIdx.x + i * 256;
    hr[s] = f2bf_rne(v[i].x * inv);
    hr[SDN + s] = f2bf_rne(v[i].y * inv);
  }
}

// ---------------- simpson + RMS + MIMO + conj(phi) + tau/beta ----------------
__global__ __launch_bounds__(256) void final_kernel(
    const float2* __restrict__ V, const ushort_t* __restrict__ proj,
    const float* __restrict__ mimo, const float* __restrict__ tau,
    const float* __restrict__ beta, float* __restrict__ out) {
  int bid = blockIdx.x;
  int m = ((bid & 7) << 9) | (bid >> 3);  // XCD-local consecutive m for V L2 reuse
  int t = m & (LSEQ - 1);
  __shared__ float2 hl[SDN];
  __shared__ float red[256];
  float sum = 0.f;
#pragma unroll
  for (int i = 0; i < 4; ++i) {
    int s = threadIdx.x + i * 256;
    float2 v0 = V[(size_t)m * SDN + s];
    float2 v1 = make_float2(0.f, 0.f), v2 = make_float2(0.f, 0.f);
    if (t >= 1) v1 = V[(size_t)(m - 1) * SDN + s];
    if (t >= 2) v2 = V[(size_t)(m - 2) * SDN + s];
    float2 h = make_float2((v0.x + 4.f * v1.x + v2.x) * (1.f / 6.f),
                           (v0.y + 4.f * v1.y + v2.y) * (1.f / 6.f));
    hl[s] = h;
    sum += h.x * h.x + h.y * h.y;
  }
  red[threadIdx.x] = sum;
  __syncthreads();
  for (int o = 128; o > 0; o >>= 1) {
    if (threadIdx.x < o) red[threadIdx.x] += red[threadIdx.x + o];
    __syncthreads();
  }
  float inv = 1.0f / sqrtf(red[0] * (1.f / SDN) + 1e-6f);
  float tv = tau[0], bv = beta[0];
  const ushort_t* pp = proj + ((size_t)m << 13) + 2048;  // phi columns
#pragma unroll
  for (int i = 0; i < 4; ++i) {
    int s = threadIdx.x + i * 256;
    int g = s >> 3, q = s & 7;
    const float* wp = mimo + (size_t)g * 64 + q;
    float hr = 0.f, hi = 0.f;
#pragma unroll
    for (int p = 0; p < 8; ++p) {
      float wv = wp[p * 8];
      float2 hp = hl[(g << 3) + p];
      hr = fmaf(hp.x, wv, hr);
      hi = fmaf(hp.y, wv, hi);
    }
    hr *= inv; hi *= inv;
    float o1 = hr * bf2f(pp[s]) + hi * bf2f(pp[SDN + s]);
    out[(size_t)m * SDN + s] = tv * o1 + bv;
  }
}

extern "C" void kernel_launch(void* const* d_in, const int* in_sizes, int n_in,
                              void* d_out, int out_size, void* d_ws, size_t ws_size,
                              hipStream_t stream) {
  const float* x      = (const float*)d_in[0];
  const float* z_prev = (const float*)d_in[1];
  const float* W_psi  = (const float*)d_in[2];
  const float* b_psi  = (const float*)d_in[3];
  const float* W_phi  = (const float*)d_in[4];
  const float* b_phi  = (const float*)d_in[5];
  const float* W_gate = (const float*)d_in[6];
  const float* b_gate = (const float*)d_in[7];
  const float* s_gain = (const float*)d_in[8];
  const float* omega  = (const float*)d_in[9];
  const float* log_g  = (const float*)d_in[10];
  const float* dt     = (const float*)d_in[11];
  const float* W_bs   = (const float*)d_in[12];
  const float* b_bs   = (const float*)d_in[13];
  const float* W_ps   = (const float*)d_in[14];
  const float* b_ps   = (const float*)d_in[15];
  const float* W_btx  = (const float*)d_in[16];
  const float* b_btx  = (const float*)d_in[17];
  const float* W_bth  = (const float*)d_in[18];
  const float* b_bth  = (const float*)d_in[19];
  const float* W_ptx  = (const float*)d_in[20];
  const float* b_ptx  = (const float*)d_in[21];
  const float* mimo_w = (const float*)d_in[22];
  const float* tau    = (const float*)d_in[23];
  const float* beta   = (const float*)d_in[24];
  float* out = (float*)d_out;

  float* ws = (float*)d_ws;
  const size_t M1 = 1 << 20;
  // ---- workspace layout, float units ----
  // [0,16M)   proj   : 32M bf16 = [4096][8192]
  // [16M,24M) V      : 4M float2
  // [24M,26M) xb     : 4M bf16
  // [26M,30M) wcat   : 8M bf16 [8192][1024]; P0/P1 alias after fused GEMM
  // [30M,31M) wbthb  : 2M bf16 [1024][2048]
  // [31M,35M) hflatB : 8M bf16 [4096][2048]
  // [35M,..)  bcat(8192) gate(4096) ac(2048) Ac(2048) carry(256K) prefix(256K)
  ushort_t* proj   = (ushort_t*)ws;
  float2*   V      = (float2*)(ws + 16 * M1);
  ushort_t* xb     = (ushort_t*)(ws + 24 * M1);
  ushort_t* wcat   = (ushort_t*)(ws + 26 * M1);
  ushort_t* P0     = wcat;
  ushort_t* P1     = wcat + 4u * 1024u * 1024u;
  ushort_t* wbthb  = (ushort_t*)(ws + 30 * M1);
  ushort_t* hflatB = (ushort_t*)(ws + 31 * M1);
  float*    bcat   = ws + 35 * M1;
  float*    gate   = bcat + 8192;
  float2*   ac     = (float2*)(gate + 4096);
  float2*   Ac     = ac + 1024;
  float2*   carry  = Ac + 1024;                 // 131072 float2
  float2*   prefix = carry + 131072;            // 131072 float2
  (void)ws_size; (void)in_sizes; (void)n_in; (void)out_size;

  dim3 blk(256);
  dim3 sgrid(SDN / 256, NCHUNK, BATCHN);

  // coefficients + gate + all conversions in one kernel
  coef_kernel<<<dim3(4), blk, 0, stream>>>(omega, log_g, dt, ac, Ac);
  gate_kernel<<<dim3(BLROWS / 4), blk, 0, stream>>>(x, z_prev, W_gate, b_gate, s_gain, gate);
  wcvt_kernel<<<dim3(14368), blk, 0, stream>>>(
      x, W_psi, W_phi, W_bs, W_ps, W_btx, W_ptx, W_bth,
      b_psi, b_phi, b_bs, b_ps, b_btx, b_ptx,
      xb, wcat, wbthb, bcat);

  // fused projection GEMM: [4096,1024] @ [8192,1024]^T -> proj (bf16)
  gemm_bf16<0><<<dim3(2048), blk, 0, stream>>>(xb, wcat, bcat, proj);

  // scan 1 (U_scout fused into stages)
  scan_stage1<0><<<sgrid, blk, 0, stream>>>(proj, gate, P0, P1, b_bth, ac, carry);
  scan_stage2<<<dim3(SDN / 256, 1, BATCHN), blk, 0, stream>>>(carry, Ac, prefix);
  scan_stage3<0><<<sgrid, blk, 0, stream>>>(proj, gate, P0, P1, b_bth, ac, prefix, V);

  // H_flat (bf16), split-K bth GEMM -> bf16 partials (into dead wcat)
  hflat_kernel<<<dim3(BLROWS), blk, 0, stream>>>(V, hflatB);
  gemm_bf16<1><<<dim3(8, 32, 2), blk, 0, stream>>>(hflatB, wbthb, bcat, P0);

  // scan 2 (U_true fused into stages)
  scan_stage1<1><<<sgrid, blk, 0, stream>>>(proj, gate, P0, P1, b_bth, ac, carry);
  scan_stage2<<<dim3(SDN / 256, 1, BATCHN), blk, 0, stream>>>(carry, Ac, prefix);
  scan_stage3<1><<<sgrid, blk, 0, stream>>>(proj, gate, P0, P1, b_bth, ac, prefix, V);

  // fused epilogue
  final_kernel<<<dim3(BLROWS), blk, 0, stream>>>(V, proj, mimo_w, tau, beta, out);
}

// Round 6
// 275.038 us; speedup vs baseline: 1.1153x; 1.1153x over previous
//
#include <hip/hip_runtime.h>
#include <math.h>

#define DIMX   1024
#define SDN    1024
#define BATCHN 2
#define LSEQ   2048
#define BLROWS (BATCHN*LSEQ)
#define NCHUNK 64
#define LCHUNK (LSEQ/NCHUNK)
#define PI_F   3.14159265358979f

typedef unsigned short ushort_t;
typedef __bf16 bf16_t;
typedef bf16_t bf16x8 __attribute__((ext_vector_type(8)));
typedef float f32x4 __attribute__((ext_vector_type(4)));

__device__ __forceinline__ float softplusf_(float x) {
  return x > 20.0f ? x : log1pf(expf(x));
}

__device__ __forceinline__ ushort_t f2bf_rne(float f) {
  unsigned u = __float_as_uint(f);
  u = u + 0x7fffu + ((u >> 16) & 1u);
  return (ushort_t)(u >> 16);
}

__device__ __forceinline__ float bf2f(ushort_t u) {
  return __uint_as_float(((unsigned)u) << 16);
}

__device__ __forceinline__ float2 cfma2(float2 a, float2 v, float2 u) {
  float re = fmaf(a.x, v.x, fmaf(-a.y, v.y, u.x));
  float im = fmaf(a.x, v.y, fmaf(a.y, v.x, u.y));
  return make_float2(re, im);
}

__device__ __forceinline__ void gload_lds16(const ushort_t* g, ushort_t* l) {
  __builtin_amdgcn_global_load_lds(
      (const __attribute__((address_space(1))) void*)g,
      (__attribute__((address_space(3))) void*)l, 16, 0, 0);
}

// ---------------- fused weight/x conversion + bias concat (R5, verified) ----------------
__global__ __launch_bounds__(256) void wcvt_kernel(
    const float* __restrict__ x,
    const float* __restrict__ Wpsi, const float* __restrict__ Wphi,
    const float* __restrict__ Wbs, const float* __restrict__ Wps,
    const float* __restrict__ Wbtx, const float* __restrict__ Wptx,
    const float* __restrict__ Wbth,
    const float* __restrict__ b_psi, const float* __restrict__ b_phi,
    const float* __restrict__ b_bs, const float* __restrict__ b_ps,
    const float* __restrict__ b_btx, const float* __restrict__ b_ptx,
    ushort_t* __restrict__ xb, ushort_t* __restrict__ wcat,
    ushort_t* __restrict__ wbthb, float* __restrict__ bcat) {
  int b = blockIdx.x;
  if (b >= 14336) {
    int n = (b - 14336) * 256 + threadIdx.x;
    float v;
    if (n < 2048) v = b_psi[n];
    else if (n < 4096) v = b_phi[n - 2048];
    else if (n < 5120) v = b_bs[n - 4096];
    else if (n < 6144) v = b_ps[n - 5120];
    else if (n < 7168) v = b_btx[n - 6144];
    else v = b_ptx[n - 7168];
    bcat[n] = v;
    return;
  }
  const float* src; ushort_t* dst; int off;
  if (b < 4096)       { src = x;    dst = xb;               off = b; }
  else if (b < 6144)  { src = Wpsi; dst = wcat;             off = b - 4096; }
  else if (b < 8192)  { src = Wphi; dst = wcat + 2097152u;  off = b - 6144; }
  else if (b < 9216)  { src = Wbs;  dst = wcat + 4194304u;  off = b - 8192; }
  else if (b < 10240) { src = Wps;  dst = wcat + 5242880u;  off = b - 9216; }
  else if (b < 11264) { src = Wbtx; dst = wcat + 6291456u;  off = b - 10240; }
  else if (b < 12288) { src = Wptx; dst = wcat + 7340032u;  off = b - 11264; }
  else                { src = Wbth; dst = wbthb;            off = b - 12288; }
  int i = (off * 256 + threadIdx.x) * 4;
  float4 v = *(const float4*)(src + i);
  ushort4 o;
  o.x = f2bf_rne(v.x); o.y = f2bf_rne(v.y);
  o.z = f2bf_rne(v.z); o.w = f2bf_rne(v.w);
  *(ushort4*)(dst + i) = o;
}

// ---------------- coefficients ----------------
__global__ void coef_kernel(const float* __restrict__ omega,
                            const float* __restrict__ log_gamma,
                            const float* __restrict__ dt,
                            float2* __restrict__ a_out,
                            float2* __restrict__ A_out) {
  int s = blockIdx.x * blockDim.x + threadIdx.x;
  if (s >= SDN) return;
  double dtv = (double)dt[0];
  double dte = dtv > 20.0 ? dtv : log1p(exp(dtv));
  double gam = 0.0;
  if (s < SDN - SDN / 4) {  // band0 = indices [768,1023] (freqs strictly decreasing)
    double lg = (double)log_gamma[s];
    gam = lg > 20.0 ? lg : log1p(exp(lg));
  }
  double th = (double)omega[s] * dte;
  double r  = exp(-gam * dte);
  a_out[s] = make_float2((float)(r * cos(th)), (float)(r * sin(th)));
  double thl = th * (double)LCHUNK;
  double rl  = exp(-gam * dte * (double)LCHUNK);
  A_out[s] = make_float2((float)(rl * cos(thl)), (float)(rl * sin(thl)));
}

// ---------------- gate ----------------
__global__ __launch_bounds__(256) void gate_kernel(
    const float* __restrict__ x, const float* __restrict__ z,
    const float* __restrict__ Wg, const float* __restrict__ bg,
    const float* __restrict__ sg, float* __restrict__ gate) {
  int m = blockIdx.x * 4 + (threadIdx.x >> 6);
  int lane = threadIdx.x & 63;
  const float* xp = x + (size_t)m * DIMX;
  const float* zp = z + (size_t)m * DIMX;
  float dot = 0.f, sur = 0.f;
  for (int i = lane; i < DIMX; i += 64) {
    float xv = xp[i];
    dot = fmaf(xv, Wg[i], dot);
    sur += fabsf(xv - zp[i]);
  }
#pragma unroll
  for (int o = 32; o > 0; o >>= 1) {
    dot += __shfl_down(dot, o, 64);
    sur += __shfl_down(sur, o, 64);
  }
  if (lane == 0) {
    float gs = 1.f / (1.f + expf(-(dot + bg[0])));
    gate[m] = gs * (1.f + tanhf(sg[0]) * (sur * (1.f / DIMX)));
  }
}

// ---------------- 256^2 deep-pipelined fused projection GEMM ----------------
// C[4096][8192] = A[4096][1024] @ B[8192][1024]^T + bias, bf16 out, fp32 acc.
// 8 waves (2M x 4N), BK=32, 3 LDS buffers (96 KB), depth-2 prefetch with
// counted vmcnt(4) (T4), raw s_barrier, setprio around MFMA (T5),
// granule-rotation LDS swizzle (T2, zero-conflict-verified in R4),
// bijective 8x8-rect XCD swizzle (T1).
__global__ __launch_bounds__(512, 1) void gemm8(
    const ushort_t* __restrict__ A, const ushort_t* __restrict__ Bm,
    const float* __restrict__ bias, ushort_t* __restrict__ C) {
  __shared__ ushort_t sh[3][2][8192];  // [buf][A/B][256 rows * 32 k], rotated
  const int tid = threadIdx.x;
  const int w = tid >> 6, l = tid & 63;
  // XCD swizzle: 512 wgs, 64/XCD arranged as 8(M) x 8(N) tile rect per XCD
  int b = blockIdx.x;
  int xcd = b & 7, i_x = b >> 3;
  int tm = (xcd >> 2) * 8 + (i_x >> 3);   // 0..15
  int tn = (xcd & 3) * 8 + (i_x & 7);     // 0..31
  const int bm = tm << 8, bn = tn << 8;
  const int wr = w >> 2, wcn = w & 3;

  // staging geometry: per instr 512 lanes cover 128 rows x 4 granules(16B)
  const int row0 = tid >> 2;          // 0..127
  const int pos  = tid & 3;
  const int c0 = ((pos - (row0 >> 1)) & 3) << 3;   // content elem offset (row0 & row0+128 same)
  const ushort_t* gA0 = A  + (size_t)(bm + row0) * 1024 + c0;
  const ushort_t* gA1 = A  + (size_t)(bm + 128 + row0) * 1024 + c0;
  const ushort_t* gB0 = Bm + (size_t)(bn + row0) * 1024 + c0;
  const ushort_t* gB1 = Bm + (size_t)(bn + 128 + row0) * 1024 + c0;
  const int o0 = tid * 8;             // ushort offset: row0*32 + pos*8
  const int o1 = o0 + 4096;

#define STAGE8(bf, kt)                                \
  do {                                                \
    int k0_ = (kt) * 32;                              \
    gload_lds16(gA0 + k0_, &sh[bf][0][o0]);           \
    gload_lds16(gA1 + k0_, &sh[bf][0][o1]);           \
    gload_lds16(gB0 + k0_, &sh[bf][1][o0]);           \
    gload_lds16(gB1 + k0_, &sh[bf][1][o1]);           \
  } while (0)

  f32x4 acc[8][4] = {};
  const int rl = l & 15, kh = l >> 4;
  const int posr = ((kh + (rl >> 1)) & 3) << 3;  // rotated granule for reads

  STAGE8(0, 0);
  STAGE8(1, 1);
  asm volatile("s_waitcnt vmcnt(4)\n\ts_barrier" ::: "memory");

  int cur = 0, stg = 2;
  for (int kt = 0; kt < 32; ++kt) {
    if (kt + 2 < 32) STAGE8(stg, kt + 2);
    const ushort_t* Ab = sh[cur][0];
    const ushort_t* Bb = sh[cur][1];
    uint4 af[8], bf_[4];
#pragma unroll
    for (int j = 0; j < 4; ++j) {
      int r = wcn * 64 + j * 16 + rl;
      bf_[j] = *(const uint4*)&Bb[r * 32 + posr];
    }
#pragma unroll
    for (int i = 0; i < 8; ++i) {
      int r = wr * 128 + i * 16 + rl;
      af[i] = *(const uint4*)&Ab[r * 32 + posr];
    }
    __builtin_amdgcn_s_setprio(1);
#pragma unroll
    for (int i = 0; i < 8; ++i)
#pragma unroll
      for (int j = 0; j < 4; ++j)
        acc[i][j] = __builtin_amdgcn_mfma_f32_16x16x32_bf16(
            __builtin_bit_cast(bf16x8, af[i]), __builtin_bit_cast(bf16x8, bf_[j]),
            acc[i][j], 0, 0, 0);
    __builtin_amdgcn_s_setprio(0);
    if (kt < 30) asm volatile("s_waitcnt vmcnt(4)\n\ts_barrier" ::: "memory");
    else         asm volatile("s_waitcnt vmcnt(0)\n\ts_barrier" ::: "memory");
    cur = (cur == 2) ? 0 : cur + 1;
    stg = (stg == 2) ? 0 : stg + 1;
  }
#undef STAGE8

#pragma unroll
  for (int i = 0; i < 8; ++i) {
    int mrow = bm + wr * 128 + i * 16 + (l >> 4) * 4;
#pragma unroll
    for (int j = 0; j < 4; ++j) {
      int ncol = bn + wcn * 64 + j * 16 + (l & 15);
      float bv = bias[ncol];
#pragma unroll
      for (int r = 0; r < 4; ++r)
        C[(size_t)(mrow + r) * 8192 + ncol] = f2bf_rne(acc[i][j][r] + bv);
    }
  }
}

// ---------------- 128^2 split-K GEMM for bth (R4, verified) ----------------
template<int MODE>
__global__ __launch_bounds__(256, 2) void gemm_bf16(
    const ushort_t* __restrict__ Xb, const ushort_t* __restrict__ Wb,
    const float* __restrict__ bias, ushort_t* __restrict__ Cb) {
  __shared__ ushort_t As[2][4096];
  __shared__ ushort_t Bs[2][4096];
  const int tid = threadIdx.x;
  const int w = tid >> 6, l = tid & 63;
  int bm, bn, ldx, ldw;
  const ushort_t *Xp, *Wp;
  if (MODE == 0) {
    int b = blockIdx.x;
    int xcd = b & 7, idx = b >> 3;
    int tx = ((xcd & 3) << 4) + (idx & 15);
    int ty = ((xcd >> 2) << 4) + (idx >> 4);
    bm = ty << 7; bn = tx << 7;
    ldx = 1024; ldw = 1024;
    Xp = Xb; Wp = Wb;
  } else {
    bm = blockIdx.y << 7; bn = blockIdx.x << 7;
    ldx = 2048; ldw = 2048;
    Xp = Xb + blockIdx.z * 1024;
    Wp = Wb + blockIdx.z * 1024;
  }
  const int wr = w >> 1, wc = w & 1;

  const int srow = tid >> 2;
  const int c8 = (((tid & 3) - (tid >> 3)) & 3) << 3;
  const ushort_t* ga0 = Xp + (size_t)(bm + srow) * ldx + c8;
  const ushort_t* ga1 = Xp + (size_t)(bm + 64 + srow) * ldx + c8;
  const ushort_t* gb0 = Wp + (size_t)(bn + srow) * ldw + c8;
  const ushort_t* gb1 = Wp + (size_t)(bn + 64 + srow) * ldw + c8;

  f32x4 acc[4][4] = {};
  const int nk = (MODE == 0) ? 32 : 32;

#define STAGE(buf, kt)                                   \
  do {                                                   \
    gload_lds16(ga0 + (kt), &As[buf][w * 512]);          \
    gload_lds16(ga1 + (kt), &As[buf][2048 + w * 512]);   \
    gload_lds16(gb0 + (kt), &Bs[buf][w * 512]);          \
    gload_lds16(gb1 + (kt), &Bs[buf][2048 + w * 512]);   \
  } while (0)

  STAGE(0, 0);
  __syncthreads();

  const int rl = l & 15, kh = l >> 4;
  const int chunkp = (kh + (rl >> 1)) & 3;
  for (int kt = 0; kt < nk; ++kt) {
    int cur = kt & 1;
    if (kt + 1 < nk) STAGE(cur ^ 1, (kt + 1) * 32);
    const uint4* Af = (const uint4*)As[cur];
    const uint4* Bf = (const uint4*)Bs[cur];
    bf16x8 a[4], b[4];
#pragma unroll
    for (int i = 0; i < 4; ++i)
      a[i] = __builtin_bit_cast(bf16x8, Af[(wr * 64 + i * 16 + rl) * 4 + chunkp]);
#pragma unroll
    for (int j = 0; j < 4; ++j)
      b[j] = __builtin_bit_cast(bf16x8, Bf[(wc * 64 + j * 16 + rl) * 4 + chunkp]);
#pragma unroll
    for (int i = 0; i < 4; ++i)
#pragma unroll
      for (int j = 0; j < 4; ++j)
        acc[i][j] = __builtin_amdgcn_mfma_f32_16x16x32_bf16(a[i], b[j], acc[i][j], 0, 0, 0);
    __syncthreads();
  }
#undef STAGE

#pragma unroll
  for (int i = 0; i < 4; ++i) {
    int mrow = bm + wr * 64 + i * 16 + (l >> 4) * 4;
#pragma unroll
    for (int j = 0; j < 4; ++j) {
      int ncol = bn + wc * 64 + j * 16 + (l & 15);
      if (MODE == 0) {
        float bv = bias[ncol];
#pragma unroll
        for (int r = 0; r < 4; ++r)
          Cb[(size_t)(mrow + r) * 8192 + ncol] = f2bf_rne(acc[i][j][r] + bv);
      } else {
        ushort_t* P = Cb + (size_t)blockIdx.z * (4096u * 1024u);
#pragma unroll
        for (int r = 0; r < 4; ++r)
          P[(size_t)(mrow + r) * 1024 + ncol] = f2bf_rne(acc[i][j][r]);
      }
    }
  }
}

// proj row layout (8192 bf16): psi_re | psi_im | phi_re | phi_im | bs | ps | btx | ptx

// ---------------- U_scout (R4, verified) ----------------
__global__ __launch_bounds__(256) void u_scout(
    const float* __restrict__ gate, const ushort_t* __restrict__ proj,
    float2* __restrict__ U) {
  int idx = blockIdx.x * 256 + threadIdx.x;
  int m = idx >> 10, s = idx & (SDN - 1);
  const ushort_t* pr = proj + ((size_t)m << 13);
  float g  = gate[m];
  float bv = softplusf_(bf2f(pr[4096 + s]));
  float ph = PI_F * tanhf(bf2f(pr[5120 + s]));
  float sph, cph;
  sincosf(ph, &sph, &cph);
  float br = bv * cph, bi = bv * sph;
  float pre = bf2f(pr[s]), pim = bf2f(pr[1024 + s]);
  U[idx] = make_float2(g * (br * pre - bi * pim), g * (br * pim + bi * pre));
}

// ---------------- U_true (R4, verified) ----------------
__global__ __launch_bounds__(256) void u_true(
    const float* __restrict__ gate, const ushort_t* __restrict__ proj,
    const ushort_t* __restrict__ P0, const ushort_t* __restrict__ P1,
    const float* __restrict__ b_bth, float2* __restrict__ U) {
  int idx = blockIdx.x * 256 + threadIdx.x;
  int m = idx >> 10, s = idx & (SDN - 1);
  const ushort_t* pr = proj + ((size_t)m << 13);
  float g  = gate[m];
  float blv = bf2f(pr[6144 + s]) + bf2f(P0[idx]) + bf2f(P1[idx]) + b_bth[s];
  float bv = softplusf_(blv);
  float ph = PI_F * tanhf(bf2f(pr[7168 + s]));
  float sph, cph;
  sincosf(ph, &sph, &cph);
  float br = bv * cph, bi = bv * sph;
  float pre = bf2f(pr[s]), pim = bf2f(pr[1024 + s]);
  U[idx] = make_float2(g * (br * pre - bi * pim), g * (br * pim + bi * pre));
}

// ---------------- chunked parallel scan (R4, verified) ----------------
__global__ __launch_bounds__(256) void scan_stage1(
    const float2* __restrict__ U, const float2* __restrict__ a,
    float2* __restrict__ carry) {
  int s = blockIdx.x * 256 + threadIdx.x;
  int c = blockIdx.y, b = blockIdx.z;
  float2 av = a[s];
  float2 V = make_float2(0.f, 0.f);
  const float2* Up = U + (size_t)(b * LSEQ + c * LCHUNK) * SDN + s;
#pragma unroll 4
  for (int t = 0; t < LCHUNK; ++t)
    V = cfma2(av, V, Up[(size_t)t * SDN]);
  carry[(size_t)(b * NCHUNK + c) * SDN + s] = V;
}

__global__ __launch_bounds__(256) void scan_stage2(
    const float2* __restrict__ carry, const float2* __restrict__ A,
    float2* __restrict__ prefix) {
  int s = blockIdx.x * 256 + threadIdx.x;
  int b = blockIdx.z;
  float2 Av = A[s];
  float2 P = make_float2(0.f, 0.f);
  for (int c = 0; c < NCHUNK; ++c) {
    size_t off = (size_t)(b * NCHUNK + c) * SDN + s;
    prefix[off] = P;
    P = cfma2(Av, P, carry[off]);
  }
}

__global__ __launch_bounds__(256) void scan_stage3(
    const float2* __restrict__ U, const float2* __restrict__ a,
    const float2* __restrict__ prefix, float2* __restrict__ Vout) {
  int s = blockIdx.x * 256 + threadIdx.x;
  int c = blockIdx.y, b = blockIdx.z;
  float2 av = a[s];
  float2 V = prefix[(size_t)(b * NCHUNK + c) * SDN + s];
  size_t base = (size_t)(b * LSEQ + c * LCHUNK) * SDN + s;
#pragma unroll 4
  for (int t = 0; t < LCHUNK; ++t) {
    V = cfma2(av, V, U[base + (size_t)t * SDN]);
    Vout[base + (size_t)t * SDN] = V;
  }
}

// ---------------- H_flat (R4, verified) ----------------
__global__ __launch_bounds__(256) void hflat_kernel(
    const float2* __restrict__ V, ushort_t* __restrict__ Hflat) {
  int m = blockIdx.x;
  int t = m & (LSEQ - 1);
  float2 v[4];
  float sum = 0.f;
#pragma unroll
  for (int i = 0; i < 4; ++i) {
    int s = threadIdx.x + i * 256;
    float2 vv = make_float2(0.f, 0.f);
    if (t > 0) vv = V[(size_t)(m - 1) * SDN + s];
    v[i] = vv;
    sum += vv.x * vv.x + vv.y * vv.y;
  }
  __shared__ float red[256];
  red[threadIdx.x] = sum;
  __syncthreads();
  for (int o = 128; o > 0; o >>= 1) {
    if (threadIdx.x < o) red[threadIdx.x] += red[threadIdx.x + o];
    __syncthreads();
  }
  float inv = 1.0f / sqrtf(red[0] * (1.f / SDN) + 1e-6f);
  ushort_t* hr = Hflat + ((size_t)m << 11);
#pragma unroll
  for (int i = 0; i < 4; ++i) {
    int s = threadIdx.x + i * 256;
    hr[s] = f2bf_rne(v[i].x * inv);
    hr[SDN + s] = f2bf_rne(v[i].y * inv);
  }
}

// ---------------- final epilogue (R4, verified) ----------------
__global__ __launch_bounds__(256) void final_kernel(
    const float2* __restrict__ V, const ushort_t* __restrict__ proj,
    const float* __restrict__ mimo, const float* __restrict__ tau,
    const float* __restrict__ beta, float* __restrict__ out) {
  int bid = blockIdx.x;
  int m = ((bid & 7) << 9) | (bid >> 3);
  int t = m & (LSEQ - 1);
  __shared__ float2 hl[SDN];
  __shared__ float red[256];
  float sum = 0.f;
#pragma unroll
  for (int i = 0; i < 4; ++i) {
    int s = threadIdx.x + i * 256;
    float2 v0 = V[(size_t)m * SDN + s];
    float2 v1 = make_float2(0.f, 0.f), v2 = make_float2(0.f, 0.f);
    if (t >= 1) v1 = V[(size_t)(m - 1) * SDN + s];
    if (t >= 2) v2 = V[(size_t)(m - 2) * SDN + s];
    float2 h = make_float2((v0.x + 4.f * v1.x + v2.x) * (1.f / 6.f),
                           (v0.y + 4.f * v1.y + v2.y) * (1.f / 6.f));
    hl[s] = h;
    sum += h.x * h.x + h.y * h.y;
  }
  red[threadIdx.x] = sum;
  __syncthreads();
  for (int o = 128; o > 0; o >>= 1) {
    if (threadIdx.x < o) red[threadIdx.x] += red[threadIdx.x + o];
    __syncthreads();
  }
  float inv = 1.0f / sqrtf(red[0] * (1.f / SDN) + 1e-6f);
  float tv = tau[0], bv = beta[0];
  const ushort_t* pp = proj + ((size_t)m << 13) + 2048;
#pragma unroll
  for (int i = 0; i < 4; ++i) {
    int s = threadIdx.x + i * 256;
    int g = s >> 3, q = s & 7;
    const float* wp = mimo + (size_t)g * 64 + q;
    float hr = 0.f, hi = 0.f;
#pragma unroll
    for (int p = 0; p < 8; ++p) {
      float wv = wp[p * 8];
      float2 hp = hl[(g << 3) + p];
      hr = fmaf(hp.x, wv, hr);
      hi = fmaf(hp.y, wv, hi);
    }
    hr *= inv; hi *= inv;
    float o1 = hr * bf2f(pp[s]) + hi * bf2f(pp[SDN + s]);
    out[(size_t)m * SDN + s] = tv * o1 + bv;
  }
}

extern "C" void kernel_launch(void* const* d_in, const int* in_sizes, int n_in,
                              void* d_out, int out_size, void* d_ws, size_t ws_size,
                              hipStream_t stream) {
  const float* x      = (const float*)d_in[0];
  const float* z_prev = (const float*)d_in[1];
  const float* W_psi  = (const float*)d_in[2];
  const float* b_psi  = (const float*)d_in[3];
  const float* W_phi  = (const float*)d_in[4];
  const float* b_phi  = (const float*)d_in[5];
  const float* W_gate = (const float*)d_in[6];
  const float* b_gate = (const float*)d_in[7];
  const float* s_gain = (const float*)d_in[8];
  const float* omega  = (const float*)d_in[9];
  const float* log_g  = (const float*)d_in[10];
  const float* dt     = (const float*)d_in[11];
  const float* W_bs   = (const float*)d_in[12];
  const float* b_bs   = (const float*)d_in[13];
  const float* W_ps   = (const float*)d_in[14];
  const float* b_ps   = (const float*)d_in[15];
  const float* W_btx  = (const float*)d_in[16];
  const float* b_btx  = (const float*)d_in[17];
  const float* W_bth  = (const float*)d_in[18];
  const float* b_bth  = (const float*)d_in[19];
  const float* W_ptx  = (const float*)d_in[20];
  const float* b_ptx  = (const float*)d_in[21];
  const float* mimo_w = (const float*)d_in[22];
  const float* tau    = (const float*)d_in[23];
  const float* beta   = (const float*)d_in[24];
  float* out = (float*)d_out;

  float* ws = (float*)d_ws;
  const size_t M1 = 1 << 20;
  // ---- workspace layout, float units ----
  // [0,16M)   proj   : 32M bf16 = [4096][8192]
  // [16M,24M) U/V    : 4M float2 (scan in-place)
  // [24M,26M) xb     : 4M bf16
  // [26M,30M) wcat   : 8M bf16 [8192][1024]; P0/P1 alias after fused GEMM
  // [30M,31M) wbthb  : 2M bf16 [1024][2048]
  // [31M,35M) hflatB : 8M bf16 [4096][2048]
  // [35M,..)  bcat(8192) gate(4096) ac(2048) Ac(2048) carry(256K) prefix(256K)
  ushort_t* proj   = (ushort_t*)ws;
  float2*   U      = (float2*)(ws + 16 * M1);
  float2*   V      = U;
  ushort_t* xb     = (ushort_t*)(ws + 24 * M1);
  ushort_t* wcat   = (ushort_t*)(ws + 26 * M1);
  ushort_t* P0     = wcat;
  ushort_t* P1     = wcat + 4u * 1024u * 1024u;
  ushort_t* wbthb  = (ushort_t*)(ws + 30 * M1);
  ushort_t* hflatB = (ushort_t*)(ws + 31 * M1);
  float*    bcat   = ws + 35 * M1;
  float*    gate   = bcat + 8192;
  float2*   ac     = (float2*)(gate + 4096);
  float2*   Ac     = ac + 1024;
  float2*   carry  = Ac + 1024;                 // 131072 float2
  float2*   prefix = carry + 131072;            // 131072 float2
  (void)ws_size; (void)in_sizes; (void)n_in; (void)out_size;

  dim3 blk(256);
  dim3 sgrid(SDN / 256, NCHUNK, BATCHN);

  coef_kernel<<<dim3(4), blk, 0, stream>>>(omega, log_g, dt, ac, Ac);
  gate_kernel<<<dim3(BLROWS / 4), blk, 0, stream>>>(x, z_prev, W_gate, b_gate, s_gain, gate);
  wcvt_kernel<<<dim3(14368), blk, 0, stream>>>(
      x, W_psi, W_phi, W_bs, W_ps, W_btx, W_ptx, W_bth,
      b_psi, b_phi, b_bs, b_ps, b_btx, b_ptx,
      xb, wcat, wbthb, bcat);

  // fused projection GEMM: 256^2 deep-pipelined
  gemm8<<<dim3(512), dim3(512), 0, stream>>>(xb, wcat, bcat, proj);

  // U_scout, scan 1
  u_scout<<<dim3(BLROWS * SDN / 256), blk, 0, stream>>>(gate, proj, U);
  scan_stage1<<<sgrid, blk, 0, stream>>>(U, ac, carry);
  scan_stage2<<<dim3(SDN / 256, 1, BATCHN), blk, 0, stream>>>(carry, Ac, prefix);
  scan_stage3<<<sgrid, blk, 0, stream>>>(U, ac, prefix, V);

  // H_flat, split-K bth GEMM
  hflat_kernel<<<dim3(BLROWS), blk, 0, stream>>>(V, hflatB);
  gemm_bf16<1><<<dim3(8, 32, 2), blk, 0, stream>>>(hflatB, wbthb, bcat, P0);

  // U_true, scan 2
  u_true<<<dim3(BLROWS * SDN / 256), blk, 0, stream>>>(gate, proj, P0, P1, b_bth, U);
  scan_stage1<<<sgrid, blk, 0, stream>>>(U, ac, carry);
  scan_stage2<<<dim3(SDN / 256, 1, BATCHN), blk, 0, stream>>>(carry, Ac, prefix);
  scan_stage3<<<sgrid, blk, 0, stream>>>(U, ac, prefix, V);

  // fused epilogue
  final_kernel<<<dim3(BLROWS), blk, 0, stream>>>(V, proj, mimo_w, tau, beta, out);
}

// Round 7
// 239.212 us; speedup vs baseline: 1.2823x; 1.1498x over previous
//
#include <hip/hip_runtime.h>
#include <math.h>

#define DIMX   1024
#define SDN    1024
#define BATCHN 2
#define LSEQ   2048
#define BLROWS (BATCHN*LSEQ)
#define NCHUNK 64
#define LCHUNK (LSEQ/NCHUNK)
#define PI_F   3.14159265358979f

typedef unsigned short ushort_t;
typedef unsigned int uint_t;
typedef __bf16 bf16_t;
typedef bf16_t bf16x8 __attribute__((ext_vector_type(8)));
typedef float f32x4 __attribute__((ext_vector_type(4)));

__device__ __forceinline__ float softplusf_(float x) {
  return x > 20.0f ? x : log1pf(expf(x));
}

__device__ __forceinline__ ushort_t f2bf_rne(float f) {
  unsigned u = __float_as_uint(f);
  u = u + 0x7fffu + ((u >> 16) & 1u);
  return (ushort_t)(u >> 16);
}

__device__ __forceinline__ float bf2f(ushort_t u) {
  return __uint_as_float(((unsigned)u) << 16);
}

// pack float2 -> 2x bf16 in a uint (lo = .x, hi = .y)
__device__ __forceinline__ uint_t pk2(float2 v) {
  return (uint_t)f2bf_rne(v.x) | ((uint_t)f2bf_rne(v.y) << 16);
}
__device__ __forceinline__ float2 upk2(uint_t u) {
  return make_float2(__uint_as_float(u << 16), __uint_as_float(u & 0xffff0000u));
}

__device__ __forceinline__ float2 cfma2(float2 a, float2 v, float2 u) {
  float re = fmaf(a.x, v.x, fmaf(-a.y, v.y, u.x));
  float im = fmaf(a.x, v.y, fmaf(a.y, v.x, u.y));
  return make_float2(re, im);
}

__device__ __forceinline__ void gload_lds16(const ushort_t* g, ushort_t* l) {
  __builtin_amdgcn_global_load_lds(
      (const __attribute__((address_space(1))) void*)g,
      (__attribute__((address_space(3))) void*)l, 16, 0, 0);
}

// ---------------- fused weight/x conversion + bias concat ----------------
__global__ __launch_bounds__(256) void wcvt_kernel(
    const float* __restrict__ x,
    const float* __restrict__ Wpsi, const float* __restrict__ Wphi,
    const float* __restrict__ Wbs, const float* __restrict__ Wps,
    const float* __restrict__ Wbtx, const float* __restrict__ Wptx,
    const float* __restrict__ Wbth,
    const float* __restrict__ b_psi, const float* __restrict__ b_phi,
    const float* __restrict__ b_bs, const float* __restrict__ b_ps,
    const float* __restrict__ b_btx, const float* __restrict__ b_ptx,
    ushort_t* __restrict__ xb, ushort_t* __restrict__ wcat,
    ushort_t* __restrict__ wbthb, float* __restrict__ bcat) {
  int b = blockIdx.x;
  if (b >= 14336) {
    int n = (b - 14336) * 256 + threadIdx.x;
    float v;
    if (n < 2048) v = b_psi[n];
    else if (n < 4096) v = b_phi[n - 2048];
    else if (n < 5120) v = b_bs[n - 4096];
    else if (n < 6144) v = b_ps[n - 5120];
    else if (n < 7168) v = b_btx[n - 6144];
    else v = b_ptx[n - 7168];
    bcat[n] = v;
    return;
  }
  const float* src; ushort_t* dst; int off;
  if (b < 4096)       { src = x;    dst = xb;               off = b; }
  else if (b < 6144)  { src = Wpsi; dst = wcat;             off = b - 4096; }
  else if (b < 8192)  { src = Wphi; dst = wcat + 2097152u;  off = b - 6144; }
  else if (b < 9216)  { src = Wbs;  dst = wcat + 4194304u;  off = b - 8192; }
  else if (b < 10240) { src = Wps;  dst = wcat + 5242880u;  off = b - 9216; }
  else if (b < 11264) { src = Wbtx; dst = wcat + 6291456u;  off = b - 10240; }
  else if (b < 12288) { src = Wptx; dst = wcat + 7340032u;  off = b - 11264; }
  else                { src = Wbth; dst = wbthb;            off = b - 12288; }
  int i = (off * 256 + threadIdx.x) * 4;
  float4 v = *(const float4*)(src + i);
  ushort4 o;
  o.x = f2bf_rne(v.x); o.y = f2bf_rne(v.y);
  o.z = f2bf_rne(v.z); o.w = f2bf_rne(v.w);
  *(ushort4*)(dst + i) = o;
}

// ---------------- coefficients ----------------
__global__ void coef_kernel(const float* __restrict__ omega,
                            const float* __restrict__ log_gamma,
                            const float* __restrict__ dt,
                            float2* __restrict__ a_out,
                            float2* __restrict__ A_out) {
  int s = blockIdx.x * blockDim.x + threadIdx.x;
  if (s >= SDN) return;
  double dtv = (double)dt[0];
  double dte = dtv > 20.0 ? dtv : log1p(exp(dtv));
  double gam = 0.0;
  if (s < SDN - SDN / 4) {  // band0 = indices [768,1023] (freqs strictly decreasing)
    double lg = (double)log_gamma[s];
    gam = lg > 20.0 ? lg : log1p(exp(lg));
  }
  double th = (double)omega[s] * dte;
  double r  = exp(-gam * dte);
  a_out[s] = make_float2((float)(r * cos(th)), (float)(r * sin(th)));
  double thl = th * (double)LCHUNK;
  double rl  = exp(-gam * dte * (double)LCHUNK);
  A_out[s] = make_float2((float)(rl * cos(thl)), (float)(rl * sin(thl)));
}

// ---------------- gate ----------------
__global__ __launch_bounds__(256) void gate_kernel(
    const float* __restrict__ x, const float* __restrict__ z,
    const float* __restrict__ Wg, const float* __restrict__ bg,
    const float* __restrict__ sg, float* __restrict__ gate) {
  int m = blockIdx.x * 4 + (threadIdx.x >> 6);
  int lane = threadIdx.x & 63;
  const float* xp = x + (size_t)m * DIMX;
  const float* zp = z + (size_t)m * DIMX;
  float dot = 0.f, sur = 0.f;
  for (int i = lane; i < DIMX; i += 64) {
    float xv = xp[i];
    dot = fmaf(xv, Wg[i], dot);
    sur += fabsf(xv - zp[i]);
  }
#pragma unroll
  for (int o = 32; o > 0; o >>= 1) {
    dot += __shfl_down(dot, o, 64);
    sur += __shfl_down(sur, o, 64);
  }
  if (lane == 0) {
    float gs = 1.f / (1.f + expf(-(dot + bg[0])));
    gate[m] = gs * (1.f + tanhf(sg[0]) * (sur * (1.f / DIMX)));
  }
}

// ---------------- bf16 MFMA GEMM (R4-verified: 90us, MfmaUtil 34%, 0 conflicts) ----------------
// MODE 0: fused x-projection. grid=2048 1-D, XCD-rect tiles, K=1024, N=8192.
// MODE 1: split-K bth. grid (8,32,2).
template<int MODE>
__global__ __launch_bounds__(256, 2) void gemm_bf16(
    const ushort_t* __restrict__ Xb, const ushort_t* __restrict__ Wb,
    const float* __restrict__ bias, ushort_t* __restrict__ Cb) {
  __shared__ ushort_t As[2][4096];
  __shared__ ushort_t Bs[2][4096];
  const int tid = threadIdx.x;
  const int w = tid >> 6, l = tid & 63;
  int bm, bn, ldx, ldw;
  const ushort_t *Xp, *Wp;
  if (MODE == 0) {
    int b = blockIdx.x;
    int xcd = b & 7, idx = b >> 3;
    int tx = ((xcd & 3) << 4) + (idx & 15);
    int ty = ((xcd >> 2) << 4) + (idx >> 4);
    bm = ty << 7; bn = tx << 7;
    ldx = 1024; ldw = 1024;
    Xp = Xb; Wp = Wb;
  } else {
    bm = blockIdx.y << 7; bn = blockIdx.x << 7;
    ldx = 2048; ldw = 2048;
    Xp = Xb + blockIdx.z * 1024;
    Wp = Wb + blockIdx.z * 1024;
  }
  const int wr = w >> 1, wc = w & 1;

  const int srow = tid >> 2;
  const int c8 = (((tid & 3) - (tid >> 3)) & 3) << 3;
  const ushort_t* ga0 = Xp + (size_t)(bm + srow) * ldx + c8;
  const ushort_t* ga1 = Xp + (size_t)(bm + 64 + srow) * ldx + c8;
  const ushort_t* gb0 = Wp + (size_t)(bn + srow) * ldw + c8;
  const ushort_t* gb1 = Wp + (size_t)(bn + 64 + srow) * ldw + c8;

  f32x4 acc[4][4] = {};
  const int nk = 32;

#define STAGE(buf, kt)                                   \
  do {                                                   \
    gload_lds16(ga0 + (kt), &As[buf][w * 512]);          \
    gload_lds16(ga1 + (kt), &As[buf][2048 + w * 512]);   \
    gload_lds16(gb0 + (kt), &Bs[buf][w * 512]);          \
    gload_lds16(gb1 + (kt), &Bs[buf][2048 + w * 512]);   \
  } while (0)

  STAGE(0, 0);
  __syncthreads();

  const int rl = l & 15, kh = l >> 4;
  const int chunkp = (kh + (rl >> 1)) & 3;
  for (int kt = 0; kt < nk; ++kt) {
    int cur = kt & 1;
    if (kt + 1 < nk) STAGE(cur ^ 1, (kt + 1) * 32);
    const uint4* Af = (const uint4*)As[cur];
    const uint4* Bf = (const uint4*)Bs[cur];
    bf16x8 a[4], b[4];
#pragma unroll
    for (int i = 0; i < 4; ++i)
      a[i] = __builtin_bit_cast(bf16x8, Af[(wr * 64 + i * 16 + rl) * 4 + chunkp]);
#pragma unroll
    for (int j = 0; j < 4; ++j)
      b[j] = __builtin_bit_cast(bf16x8, Bf[(wc * 64 + j * 16 + rl) * 4 + chunkp]);
#pragma unroll
    for (int i = 0; i < 4; ++i)
#pragma unroll
      for (int j = 0; j < 4; ++j)
        acc[i][j] = __builtin_amdgcn_mfma_f32_16x16x32_bf16(a[i], b[j], acc[i][j], 0, 0, 0);
    __syncthreads();
  }
#undef STAGE

#pragma unroll
  for (int i = 0; i < 4; ++i) {
    int mrow = bm + wr * 64 + i * 16 + (l >> 4) * 4;
#pragma unroll
    for (int j = 0; j < 4; ++j) {
      int ncol = bn + wc * 64 + j * 16 + (l & 15);
      if (MODE == 0) {
        float bv = bias[ncol];
#pragma unroll
        for (int r = 0; r < 4; ++r)
          Cb[(size_t)(mrow + r) * 8192 + ncol] = f2bf_rne(acc[i][j][r] + bv);
      } else {
        ushort_t* P = Cb + (size_t)blockIdx.z * (4096u * 1024u);
#pragma unroll
        for (int r = 0; r < 4; ++r)
          P[(size_t)(mrow + r) * 1024 + ncol] = f2bf_rne(acc[i][j][r]);
      }
    }
  }
}

// proj row layout (8192 bf16): psi_re | psi_im | phi_re | phi_im | bs | ps | btx | ptx

// ---------------- U_scout -> packed bf16 U ----------------
__global__ __launch_bounds__(256) void u_scout(
    const float* __restrict__ gate, const ushort_t* __restrict__ proj,
    uint_t* __restrict__ U) {
  int idx = blockIdx.x * 256 + threadIdx.x;
  int m = idx >> 10, s = idx & (SDN - 1);
  const ushort_t* pr = proj + ((size_t)m << 13);
  float g  = gate[m];
  float bv = softplusf_(bf2f(pr[4096 + s]));
  float ph = PI_F * tanhf(bf2f(pr[5120 + s]));
  float sph, cph;
  sincosf(ph, &sph, &cph);
  float br = bv * cph, bi = bv * sph;
  float pre = bf2f(pr[s]), pim = bf2f(pr[1024 + s]);
  U[idx] = pk2(make_float2(g * (br * pre - bi * pim), g * (br * pim + bi * pre)));
}

// ---------------- U_true -> packed bf16 U ----------------
__global__ __launch_bounds__(256) void u_true(
    const float* __restrict__ gate, const ushort_t* __restrict__ proj,
    const ushort_t* __restrict__ P0, const ushort_t* __restrict__ P1,
    const float* __restrict__ b_bth, uint_t* __restrict__ U) {
  int idx = blockIdx.x * 256 + threadIdx.x;
  int m = idx >> 10, s = idx & (SDN - 1);
  const ushort_t* pr = proj + ((size_t)m << 13);
  float g  = gate[m];
  float blv = bf2f(pr[6144 + s]) + bf2f(P0[idx]) + bf2f(P1[idx]) + b_bth[s];
  float bv = softplusf_(blv);
  float ph = PI_F * tanhf(bf2f(pr[7168 + s]));
  float sph, cph;
  sincosf(ph, &sph, &cph);
  float br = bv * cph, bi = bv * sph;
  float pre = bf2f(pr[s]), pim = bf2f(pr[1024 + s]);
  U[idx] = pk2(make_float2(g * (br * pre - bi * pim), g * (br * pim + bi * pre)));
}

// ---------------- chunked parallel scan on packed-bf16 U/V, fp32 carry ----------------
__global__ __launch_bounds__(256) void scan_stage1(
    const uint_t* __restrict__ U, const float2* __restrict__ a,
    float2* __restrict__ carry) {
  int s = blockIdx.x * 256 + threadIdx.x;
  int c = blockIdx.y, b = blockIdx.z;
  float2 av = a[s];
  float2 V = make_float2(0.f, 0.f);
  const uint_t* Up = U + (size_t)(b * LSEQ + c * LCHUNK) * SDN + s;
#pragma unroll 4
  for (int t = 0; t < LCHUNK; ++t)
    V = cfma2(av, V, upk2(Up[(size_t)t * SDN]));
  carry[(size_t)(b * NCHUNK + c) * SDN + s] = V;
}

__global__ __launch_bounds__(256) void scan_stage2(
    const float2* __restrict__ carry, const float2* __restrict__ A,
    float2* __restrict__ prefix) {
  int s = blockIdx.x * 256 + threadIdx.x;
  int b = blockIdx.z;
  float2 Av = A[s];
  float2 P = make_float2(0.f, 0.f);
  for (int c = 0; c < NCHUNK; ++c) {
    size_t off = (size_t)(b * NCHUNK + c) * SDN + s;
    prefix[off] = P;
    P = cfma2(Av, P, carry[off]);
  }
}

// in-place: Vout aliases U (read-then-write per element)
__global__ __launch_bounds__(256) void scan_stage3(
    const uint_t* __restrict__ U, const float2* __restrict__ a,
    const float2* __restrict__ prefix, uint_t* __restrict__ Vout) {
  int s = blockIdx.x * 256 + threadIdx.x;
  int c = blockIdx.y, b = blockIdx.z;
  float2 av = a[s];
  float2 V = prefix[(size_t)(b * NCHUNK + c) * SDN + s];
  size_t base = (size_t)(b * LSEQ + c * LCHUNK) * SDN + s;
#pragma unroll 4
  for (int t = 0; t < LCHUNK; ++t) {
    V = cfma2(av, V, upk2(U[base + (size_t)t * SDN]));
    Vout[base + (size_t)t * SDN] = pk2(V);
  }
}

// ---------------- H_flat (bf16) from packed V ----------------
__global__ __launch_bounds__(256) void hflat_kernel(
    const uint_t* __restrict__ V, ushort_t* __restrict__ Hflat) {
  int m = blockIdx.x;
  int t = m & (LSEQ - 1);
  float2 v[4];
  float sum = 0.f;
#pragma unroll
  for (int i = 0; i < 4; ++i) {
    int s = threadIdx.x + i * 256;
    float2 vv = make_float2(0.f, 0.f);
    if (t > 0) vv = upk2(V[(size_t)(m - 1) * SDN + s]);
    v[i] = vv;
    sum += vv.x * vv.x + vv.y * vv.y;
  }
  __shared__ float red[256];
  red[threadIdx.x] = sum;
  __syncthreads();
  for (int o = 128; o > 0; o >>= 1) {
    if (threadIdx.x < o) red[threadIdx.x] += red[threadIdx.x + o];
    __syncthreads();
  }
  float inv = 1.0f / sqrtf(red[0] * (1.f / SDN) + 1e-6f);
  ushort_t* hr = Hflat + ((size_t)m << 11);
#pragma unroll
  for (int i = 0; i < 4; ++i) {
    int s = threadIdx.x + i * 256;
    hr[s] = f2bf_rne(v[i].x * inv);
    hr[SDN + s] = f2bf_rne(v[i].y * inv);
  }
}

// ---------------- simpson + RMS + MIMO + conj(phi) + tau/beta ----------------
__global__ __launch_bounds__(256) void final_kernel(
    const uint_t* __restrict__ V, const ushort_t* __restrict__ proj,
    const float* __restrict__ mimo, const float* __restrict__ tau,
    const float* __restrict__ beta, float* __restrict__ out) {
  int bid = blockIdx.x;
  int m = ((bid & 7) << 9) | (bid >> 3);
  int t = m & (LSEQ - 1);
  __shared__ float2 hl[SDN];
  __shared__ float red[256];
  float sum = 0.f;
#pragma unroll
  for (int i = 0; i < 4; ++i) {
    int s = threadIdx.x + i * 256;
    float2 v0 = upk2(V[(size_t)m * SDN + s]);
    float2 v1 = make_float2(0.f, 0.f), v2 = make_float2(0.f, 0.f);
    if (t >= 1) v1 = upk2(V[(size_t)(m - 1) * SDN + s]);
    if (t >= 2) v2 = upk2(V[(size_t)(m - 2) * SDN + s]);
    float2 h = make_float2((v0.x + 4.f * v1.x + v2.x) * (1.f / 6.f),
                           (v0.y + 4.f * v1.y + v2.y) * (1.f / 6.f));
    hl[s] = h;
    sum += h.x * h.x + h.y * h.y;
  }
  red[threadIdx.x] = sum;
  __syncthreads();
  for (int o = 128; o > 0; o >>= 1) {
    if (threadIdx.x < o) red[threadIdx.x] += red[threadIdx.x + o];
    __syncthreads();
  }
  float inv = 1.0f / sqrtf(red[0] * (1.f / SDN) + 1e-6f);
  float tv = tau[0], bv = beta[0];
  const ushort_t* pp = proj + ((size_t)m << 13) + 2048;
#pragma unroll
  for (int i = 0; i < 4; ++i) {
    int s = threadIdx.x + i * 256;
    int g = s >> 3, q = s & 7;
    const float* wp = mimo + (size_t)g * 64 + q;
    float hr = 0.f, hi = 0.f;
#pragma unroll
    for (int p = 0; p < 8; ++p) {
      float wv = wp[p * 8];
      float2 hp = hl[(g << 3) + p];
      hr = fmaf(hp.x, wv, hr);
      hi = fmaf(hp.y, wv, hi);
    }
    hr *= inv; hi *= inv;
    float o1 = hr * bf2f(pp[s]) + hi * bf2f(pp[SDN + s]);
    out[(size_t)m * SDN + s] = tv * o1 + bv;
  }
}

extern "C" void kernel_launch(void* const* d_in, const int* in_sizes, int n_in,
                              void* d_out, int out_size, void* d_ws, size_t ws_size,
                              hipStream_t stream) {
  const float* x      = (const float*)d_in[0];
  const float* z_prev = (const float*)d_in[1];
  const float* W_psi  = (const float*)d_in[2];
  const float* b_psi  = (const float*)d_in[3];
  const float* W_phi  = (const float*)d_in[4];
  const float* b_phi  = (const float*)d_in[5];
  const float* W_gate = (const float*)d_in[6];
  const float* b_gate = (const float*)d_in[7];
  const float* s_gain = (const float*)d_in[8];
  const float* omega  = (const float*)d_in[9];
  const float* log_g  = (const float*)d_in[10];
  const float* dt     = (const float*)d_in[11];
  const float* W_bs   = (const float*)d_in[12];
  const float* b_bs   = (const float*)d_in[13];
  const float* W_ps   = (const float*)d_in[14];
  const float* b_ps   = (const float*)d_in[15];
  const float* W_btx  = (const float*)d_in[16];
  const float* b_btx  = (const float*)d_in[17];
  const float* W_bth  = (const float*)d_in[18];
  const float* b_bth  = (const float*)d_in[19];
  const float* W_ptx  = (const float*)d_in[20];
  const float* b_ptx  = (const float*)d_in[21];
  const float* mimo_w = (const float*)d_in[22];
  const float* tau    = (const float*)d_in[23];
  const float* beta   = (const float*)d_in[24];
  float* out = (float*)d_out;

  float* ws = (float*)d_ws;
  const size_t M1 = 1 << 20;
  // ---- workspace layout, float units ----
  // [0,16M)   proj   : 32M bf16 = [4096][8192]
  // [16M,20M) U/V    : 4M uint (packed 2x bf16), scan in-place
  // [24M,26M) xb     : 4M bf16
  // [26M,30M) wcat   : 8M bf16 [8192][1024]; P0/P1 alias after fused GEMM
  // [30M,31M) wbthb  : 2M bf16 [1024][2048]
  // [31M,35M) hflatB : 8M bf16 [4096][2048]
  // [35M,..)  bcat(8192) gate(4096) ac(2048) Ac(2048) carry(256K) prefix(256K)
  ushort_t* proj   = (ushort_t*)ws;
  uint_t*   U      = (uint_t*)(ws + 16 * M1);
  uint_t*   V      = U;
  ushort_t* xb     = (ushort_t*)(ws + 24 * M1);
  ushort_t* wcat   = (ushort_t*)(ws + 26 * M1);
  ushort_t* P0     = wcat;
  ushort_t* P1     = wcat + 4u * 1024u * 1024u;
  ushort_t* wbthb  = (ushort_t*)(ws + 30 * M1);
  ushort_t* hflatB = (ushort_t*)(ws + 31 * M1);
  float*    bcat   = ws + 35 * M1;
  float*    gate   = bcat + 8192;
  float2*   ac     = (float2*)(gate + 4096);
  float2*   Ac     = ac + 1024;
  float2*   carry  = Ac + 1024;                 // 131072 float2
  float2*   prefix = carry + 131072;            // 131072 float2
  (void)ws_size; (void)in_sizes; (void)n_in; (void)out_size;

  dim3 blk(256);
  dim3 sgrid(SDN / 256, NCHUNK, BATCHN);

  coef_kernel<<<dim3(4), blk, 0, stream>>>(omega, log_g, dt, ac, Ac);
  gate_kernel<<<dim3(BLROWS / 4), blk, 0, stream>>>(x, z_prev, W_gate, b_gate, s_gain, gate);
  wcvt_kernel<<<dim3(14368), blk, 0, stream>>>(
      x, W_psi, W_phi, W_bs, W_ps, W_btx, W_ptx, W_bth,
      b_psi, b_phi, b_bs, b_ps, b_btx, b_ptx,
      xb, wcat, wbthb, bcat);

  // fused projection GEMM (R4-verified)
  gemm_bf16<0><<<dim3(2048), blk, 0, stream>>>(xb, wcat, bcat, proj);

  // U_scout, scan 1
  u_scout<<<dim3(BLROWS * SDN / 256), blk, 0, stream>>>(gate, proj, U);
  scan_stage1<<<sgrid, blk, 0, stream>>>(U, ac, carry);
  scan_stage2<<<dim3(SDN / 256, 1, BATCHN), blk, 0, stream>>>(carry, Ac, prefix);
  scan_stage3<<<sgrid, blk, 0, stream>>>(U, ac, prefix, V);

  // H_flat, split-K bth GEMM
  hflat_kernel<<<dim3(BLROWS), blk, 0, stream>>>(V, hflatB);
  gemm_bf16<1><<<dim3(8, 32, 2), blk, 0, stream>>>(hflatB, wbthb, bcat, P0);

  // U_true, scan 2
  u_true<<<dim3(BLROWS * SDN / 256), blk, 0, stream>>>(gate, proj, P0, P1, b_bth, U);
  scan_stage1<<<sgrid, blk, 0, stream>>>(U, ac, carry);
  scan_stage2<<<dim3(SDN / 256, 1, BATCHN), blk, 0, stream>>>(carry, Ac, prefix);
  scan_stage3<<<sgrid, blk, 0, stream>>>(U, ac, prefix, V);

  // fused epilogue
  final_kernel<<<dim3(BLROWS), blk, 0, stream>>>(V, proj, mimo_w, tau, beta, out);
}

// Round 9
// 209.378 us; speedup vs baseline: 1.4650x; 1.1425x over previous
//
#include <hip/hip_runtime.h>
#include <math.h>

#define DIMX   1024
#define SDN    1024
#define BATCHN 2
#define LSEQ   2048
#define BLROWS (BATCHN*LSEQ)
#define NCHUNK 64
#define LCHUNK (LSEQ/NCHUNK)
#define PI_F   3.14159265358979f

typedef unsigned short ushort_t;
typedef unsigned int uint_t;
typedef __bf16 bf16_t;
typedef bf16_t bf16x8 __attribute__((ext_vector_type(8)));
typedef float f32x4 __attribute__((ext_vector_type(4)));

__device__ __forceinline__ ushort_t f2bf_rne(float f) {
  unsigned u = __float_as_uint(f);
  u = u + 0x7fffu + ((u >> 16) & 1u);
  return (ushort_t)(u >> 16);
}

__device__ __forceinline__ float bf2f(ushort_t u) {
  return __uint_as_float(((unsigned)u) << 16);
}

__device__ __forceinline__ uint_t pk2(float2 v) {
  return (uint_t)f2bf_rne(v.x) | ((uint_t)f2bf_rne(v.y) << 16);
}
__device__ __forceinline__ float2 upk2(uint_t u) {
  return make_float2(__uint_as_float(u << 16), __uint_as_float(u & 0xffff0000u));
}

__device__ __forceinline__ float2 cfma2(float2 a, float2 v, float2 u) {
  float re = fmaf(a.x, v.x, fmaf(-a.y, v.y, u.x));
  float im = fmaf(a.x, v.y, fmaf(a.y, v.x, u.y));
  return make_float2(re, im);
}

// fast softplus / tanh (u-kernels; ~1e-6 rel err, absorbed by bf16 noise)
__device__ __forceinline__ float fast_softplus(float x) {
  return x > 15.f ? x : __logf(1.f + __expf(x));
}
__device__ __forceinline__ float fast_tanh(float x) {
  float xc = fminf(fmaxf(x, -9.f), 9.f);
  float t = __expf(2.f * xc);
  return (t - 1.f) * __builtin_amdgcn_rcpf(t + 1.f);
}

__device__ __forceinline__ void gload_lds16(const ushort_t* g, ushort_t* l) {
  __builtin_amdgcn_global_load_lds(
      (const __attribute__((address_space(1))) void*)g,
      (__attribute__((address_space(3))) void*)l, 16, 0, 0);
}

// ---------------- mega prep kernel ----------------
// blocks [0,4096): x row -> xb + gate; [4096,14336): weight converts
// (Wpsi 2048 | Wphi 2048 | Wbs 1024 | Wps 1024 | Wbtx 1024 | Wptx 1024 | Wbth 2048);
// [14336,14368): bias concat; [14368,14372): coef.
__global__ __launch_bounds__(256) void prep_kernel(
    const float* __restrict__ x, const float* __restrict__ z_prev,
    const float* __restrict__ Wpsi, const float* __restrict__ Wphi,
    const float* __restrict__ Wbs, const float* __restrict__ Wps,
    const float* __restrict__ Wbtx, const float* __restrict__ Wptx,
    const float* __restrict__ Wbth,
    const float* __restrict__ b_psi, const float* __restrict__ b_phi,
    const float* __restrict__ b_bs, const float* __restrict__ b_ps,
    const float* __restrict__ b_btx, const float* __restrict__ b_ptx,
    const float* __restrict__ Wg, const float* __restrict__ bg,
    const float* __restrict__ sg,
    const float* __restrict__ omega, const float* __restrict__ log_gamma,
    const float* __restrict__ dt,
    ushort_t* __restrict__ xb, ushort_t* __restrict__ wcat,
    ushort_t* __restrict__ wbthb, float* __restrict__ bcat,
    float* __restrict__ gate, float2* __restrict__ a_out,
    float2* __restrict__ A_out) {
  int b = blockIdx.x;
  int tid = threadIdx.x;
  if (b < 4096) {
    // x row b: convert + gate
    int i = tid * 4;
    const float* xp = x + (size_t)b * DIMX;
    const float* zp = z_prev + (size_t)b * DIMX;
    float4 xv = *(const float4*)(xp + i);
    float4 zv = *(const float4*)(zp + i);
    float4 wv = *(const float4*)(Wg + i);
    ushort4 o;
    o.x = f2bf_rne(xv.x); o.y = f2bf_rne(xv.y);
    o.z = f2bf_rne(xv.z); o.w = f2bf_rne(xv.w);
    *(ushort4*)(xb + (size_t)b * DIMX + i) = o;
    float dot = xv.x * wv.x + xv.y * wv.y + xv.z * wv.z + xv.w * wv.w;
    float sur = fabsf(xv.x - zv.x) + fabsf(xv.y - zv.y) +
                fabsf(xv.z - zv.z) + fabsf(xv.w - zv.w);
    __shared__ float sdot[256], ssur[256];
    sdot[tid] = dot; ssur[tid] = sur;
    __syncthreads();
    for (int o_ = 128; o_ > 0; o_ >>= 1) {
      if (tid < o_) { sdot[tid] += sdot[tid + o_]; ssur[tid] += ssur[tid + o_]; }
      __syncthreads();
    }
    if (tid == 0) {
      float gs = 1.f / (1.f + expf(-(sdot[0] + bg[0])));
      gate[b] = gs * (1.f + tanhf(sg[0]) * (ssur[0] * (1.f / DIMX)));
    }
    return;
  }
  b -= 4096;
  if (b < 10240) {  // weight conversion regions: 8192 wcat + 2048 wbth
    const float* src; ushort_t* dst; int off;
    if (b < 2048)       { src = Wpsi; dst = wcat;             off = b; }
    else if (b < 4096)  { src = Wphi; dst = wcat + 2097152u;  off = b - 2048; }
    else if (b < 5120)  { src = Wbs;  dst = wcat + 4194304u;  off = b - 4096; }
    else if (b < 6144)  { src = Wps;  dst = wcat + 5242880u;  off = b - 5120; }
    else if (b < 7168)  { src = Wbtx; dst = wcat + 6291456u;  off = b - 6144; }
    else if (b < 8192)  { src = Wptx; dst = wcat + 7340032u;  off = b - 7168; }
    else                { src = Wbth; dst = wbthb;            off = b - 8192; }
    int i = (off * 256 + tid) * 4;
    float4 v = *(const float4*)(src + i);
    ushort4 o;
    o.x = f2bf_rne(v.x); o.y = f2bf_rne(v.y);
    o.z = f2bf_rne(v.z); o.w = f2bf_rne(v.w);
    *(ushort4*)(dst + i) = o;
    return;
  }
  b -= 10240;  // b now in [0,36)
  if (b < 32) {
    int n = b * 256 + tid;
    float v;
    if (n < 2048) v = b_psi[n];
    else if (n < 4096) v = b_phi[n - 2048];
    else if (n < 5120) v = b_bs[n - 4096];
    else if (n < 6144) v = b_ps[n - 5120];
    else if (n < 7168) v = b_btx[n - 6144];
    else v = b_ptx[n - 7168];
    bcat[n] = v;
    return;
  }
  // coef: 4 blocks x 256
  int s = (b - 32) * 256 + tid;
  double dtv = (double)dt[0];
  double dte = dtv > 20.0 ? dtv : log1p(exp(dtv));
  double gam = 0.0;
  if (s < SDN - SDN / 4) {  // band0 = [768,1023] (freqs strictly decreasing)
    double lg = (double)log_gamma[s];
    gam = lg > 20.0 ? lg : log1p(exp(lg));
  }
  double th = (double)omega[s] * dte;
  double r  = exp(-gam * dte);
  a_out[s] = make_float2((float)(r * cos(th)), (float)(r * sin(th)));
  double thl = th * (double)LCHUNK;
  double rl  = exp(-gam * dte * (double)LCHUNK);
  A_out[s] = make_float2((float)(rl * cos(thl)), (float)(rl * sin(thl)));
}

// ---------------- bf16 MFMA GEMM (R4-verified) ----------------
template<int MODE>
__global__ __launch_bounds__(256, 2) void gemm_bf16(
    const ushort_t* __restrict__ Xb, const ushort_t* __restrict__ Wb,
    const float* __restrict__ bias, ushort_t* __restrict__ Cb) {
  __shared__ ushort_t As[2][4096];
  __shared__ ushort_t Bs[2][4096];
  const int tid = threadIdx.x;
  const int w = tid >> 6, l = tid & 63;
  int bm, bn, ldx, ldw;
  const ushort_t *Xp, *Wp;
  if (MODE == 0) {
    int b = blockIdx.x;
    int xcd = b & 7, idx = b >> 3;
    int tx = ((xcd & 3) << 4) + (idx & 15);
    int ty = ((xcd >> 2) << 4) + (idx >> 4);
    bm = ty << 7; bn = tx << 7;
    ldx = 1024; ldw = 1024;
    Xp = Xb; Wp = Wb;
  } else {
    bm = blockIdx.y << 7; bn = blockIdx.x << 7;
    ldx = 2048; ldw = 2048;
    Xp = Xb + blockIdx.z * 1024;
    Wp = Wb + blockIdx.z * 1024;
  }
  const int wr = w >> 1, wc = w & 1;

  const int srow = tid >> 2;
  const int c8 = (((tid & 3) - (tid >> 3)) & 3) << 3;
  const ushort_t* ga0 = Xp + (size_t)(bm + srow) * ldx + c8;
  const ushort_t* ga1 = Xp + (size_t)(bm + 64 + srow) * ldx + c8;
  const ushort_t* gb0 = Wp + (size_t)(bn + srow) * ldw + c8;
  const ushort_t* gb1 = Wp + (size_t)(bn + 64 + srow) * ldw + c8;

  f32x4 acc[4][4] = {};
  const int nk = 32;

#define STAGE(buf, kt)                                   \
  do {                                                   \
    gload_lds16(ga0 + (kt), &As[buf][w * 512]);          \
    gload_lds16(ga1 + (kt), &As[buf][2048 + w * 512]);   \
    gload_lds16(gb0 + (kt), &Bs[buf][w * 512]);          \
    gload_lds16(gb1 + (kt), &Bs[buf][2048 + w * 512]);   \
  } while (0)

  STAGE(0, 0);
  __syncthreads();

  const int rl = l & 15, kh = l >> 4;
  const int chunkp = (kh + (rl >> 1)) & 3;
  for (int kt = 0; kt < nk; ++kt) {
    int cur = kt & 1;
    if (kt + 1 < nk) STAGE(cur ^ 1, (kt + 1) * 32);
    const uint4* Af = (const uint4*)As[cur];
    const uint4* Bf = (const uint4*)Bs[cur];
    bf16x8 a[4], b[4];
#pragma unroll
    for (int i = 0; i < 4; ++i)
      a[i] = __builtin_bit_cast(bf16x8, Af[(wr * 64 + i * 16 + rl) * 4 + chunkp]);
#pragma unroll
    for (int j = 0; j < 4; ++j)
      b[j] = __builtin_bit_cast(bf16x8, Bf[(wc * 64 + j * 16 + rl) * 4 + chunkp]);
#pragma unroll
    for (int i = 0; i < 4; ++i)
#pragma unroll
      for (int j = 0; j < 4; ++j)
        acc[i][j] = __builtin_amdgcn_mfma_f32_16x16x32_bf16(a[i], b[j], acc[i][j], 0, 0, 0);
    __syncthreads();
  }
#undef STAGE

#pragma unroll
  for (int i = 0; i < 4; ++i) {
    int mrow = bm + wr * 64 + i * 16 + (l >> 4) * 4;
#pragma unroll
    for (int j = 0; j < 4; ++j) {
      int ncol = bn + wc * 64 + j * 16 + (l & 15);
      if (MODE == 0) {
        float bv = bias[ncol];
#pragma unroll
        for (int r = 0; r < 4; ++r)
          Cb[(size_t)(mrow + r) * 8192 + ncol] = f2bf_rne(acc[i][j][r] + bv);
      } else {
        ushort_t* P = Cb + (size_t)blockIdx.z * (4096u * 1024u);
#pragma unroll
        for (int r = 0; r < 4; ++r)
          P[(size_t)(mrow + r) * 1024 + ncol] = f2bf_rne(acc[i][j][r]);
      }
    }
  }
}

// proj row layout (8192 bf16): psi_re | psi_im | phi_re | phi_im | bs | ps | btx | ptx

// ---------------- U_scout (2 elems/thread, fast-math) ----------------
__global__ __launch_bounds__(256) void u_scout(
    const float* __restrict__ gate, const ushort_t* __restrict__ proj,
    uint_t* __restrict__ U) {
  int idx2 = blockIdx.x * 256 + threadIdx.x;
  int m = idx2 >> 9, sp = (idx2 & 511) << 1;
  const ushort_t* pr = proj + ((size_t)m << 13);
  float g = gate[m];
  uint_t bsu = *(const uint_t*)(pr + 4096 + sp);
  uint_t psu = *(const uint_t*)(pr + 5120 + sp);
  uint_t pre = *(const uint_t*)(pr + sp);
  uint_t pim = *(const uint_t*)(pr + 1024 + sp);
  uint_t o[2];
#pragma unroll
  for (int e = 0; e < 2; ++e) {
    float bv = fast_softplus(bf2f((ushort_t)(e ? (bsu >> 16) : (bsu & 0xffff))));
    float ph = PI_F * fast_tanh(bf2f((ushort_t)(e ? (psu >> 16) : (psu & 0xffff))));
    float sph, cph;
    __sincosf(ph, &sph, &cph);
    float br = bv * cph, bi = bv * sph;
    float prf = bf2f((ushort_t)(e ? (pre >> 16) : (pre & 0xffff)));
    float pif = bf2f((ushort_t)(e ? (pim >> 16) : (pim & 0xffff)));
    o[e] = pk2(make_float2(g * (br * prf - bi * pif), g * (br * pif + bi * prf)));
  }
  *(uint2*)(U + ((size_t)m << 10) + sp) = make_uint2(o[0], o[1]);
}

// ---------------- U_true (2 elems/thread, fast-math) ----------------
__global__ __launch_bounds__(256) void u_true(
    const float* __restrict__ gate, const ushort_t* __restrict__ proj,
    const ushort_t* __restrict__ P0, const ushort_t* __restrict__ P1,
    const float* __restrict__ b_bth, uint_t* __restrict__ U) {
  int idx2 = blockIdx.x * 256 + threadIdx.x;
  int m = idx2 >> 9, sp = (idx2 & 511) << 1;
  const ushort_t* pr = proj + ((size_t)m << 13);
  float g = gate[m];
  size_t base = ((size_t)m << 10) + sp;
  uint_t btu = *(const uint_t*)(pr + 6144 + sp);
  uint_t ptu = *(const uint_t*)(pr + 7168 + sp);
  uint_t p0u = *(const uint_t*)(P0 + base);
  uint_t p1u = *(const uint_t*)(P1 + base);
  float2 bb = *(const float2*)(b_bth + sp);
  uint_t pre = *(const uint_t*)(pr + sp);
  uint_t pim = *(const uint_t*)(pr + 1024 + sp);
  uint_t o[2];
#pragma unroll
  for (int e = 0; e < 2; ++e) {
    float blv = bf2f((ushort_t)(e ? (btu >> 16) : (btu & 0xffff)))
              + bf2f((ushort_t)(e ? (p0u >> 16) : (p0u & 0xffff)))
              + bf2f((ushort_t)(e ? (p1u >> 16) : (p1u & 0xffff)))
              + (e ? bb.y : bb.x);
    float bv = fast_softplus(blv);
    float ph = PI_F * fast_tanh(bf2f((ushort_t)(e ? (ptu >> 16) : (ptu & 0xffff))));
    float sph, cph;
    __sincosf(ph, &sph, &cph);
    float br = bv * cph, bi = bv * sph;
    float prf = bf2f((ushort_t)(e ? (pre >> 16) : (pre & 0xffff)));
    float pif = bf2f((ushort_t)(e ? (pim >> 16) : (pim & 0xffff)));
    o[e] = pk2(make_float2(g * (br * prf - bi * pif), g * (br * pif + bi * prf)));
  }
  *(uint2*)(U + base) = make_uint2(o[0], o[1]);
}

// ---------------- chunked parallel scan on packed-bf16 U/V ----------------
__global__ __launch_bounds__(256) void scan_stage1(
    const uint_t* __restrict__ U, const float2* __restrict__ a,
    float2* __restrict__ carry) {
  int s = blockIdx.x * 256 + threadIdx.x;
  int c = blockIdx.y, b = blockIdx.z;
  float2 av = a[s];
  float2 V = make_float2(0.f, 0.f);
  const uint_t* Up = U + (size_t)(b * LSEQ + c * LCHUNK) * SDN + s;
#pragma unroll 8
  for (int t = 0; t < LCHUNK; ++t)
    V = cfma2(av, V, upk2(Up[(size_t)t * SDN]));
  carry[(size_t)(b * NCHUNK + c) * SDN + s] = V;
}

__global__ __launch_bounds__(256) void scan_stage2(
    const float2* __restrict__ carry, const float2* __restrict__ A,
    float2* __restrict__ prefix) {
  int s = blockIdx.x * 256 + threadIdx.x;
  int b = blockIdx.z;
  float2 Av = A[s];
  float2 P = make_float2(0.f, 0.f);
#pragma unroll 8
  for (int c = 0; c < NCHUNK; ++c) {
    size_t off = (size_t)(b * NCHUNK + c) * SDN + s;
    prefix[off] = P;
    P = cfma2(Av, P, carry[off]);
  }
}

// in-place: Vout aliases U (read-then-write per element)
__global__ __launch_bounds__(256) void scan_stage3(
    const uint_t* __restrict__ U, const float2* __restrict__ a,
    const float2* __restrict__ prefix, uint_t* __restrict__ Vout) {
  int s = blockIdx.x * 256 + threadIdx.x;
  int c = blockIdx.y, b = blockIdx.z;
  float2 av = a[s];
  float2 V = prefix[(size_t)(b * NCHUNK + c) * SDN + s];
  size_t base = (size_t)(b * LSEQ + c * LCHUNK) * SDN + s;
#pragma unroll 8
  for (int t = 0; t < LCHUNK; ++t) {
    V = cfma2(av, V, upk2(U[base + (size_t)t * SDN]));
    Vout[base + (size_t)t * SDN] = pk2(V);
  }
}

// ---------------- H_flat (bf16) from packed V ----------------
__global__ __launch_bounds__(256) void hflat_kernel(
    const uint_t* __restrict__ V, ushort_t* __restrict__ Hflat) {
  int m = blockIdx.x;
  int t = m & (LSEQ - 1);
  float2 v[4];
  float sum = 0.f;
#pragma unroll
  for (int i = 0; i < 4; ++i) {
    int s = threadIdx.x + i * 256;
    float2 vv = make_float2(0.f, 0.f);
    if (t > 0) vv = upk2(V[(size_t)(m - 1) * SDN + s]);
    v[i] = vv;
    sum += vv.x * vv.x + vv.y * vv.y;
  }
  __shared__ float red[256];
  red[threadIdx.x] = sum;
  __syncthreads();
  for (int o = 128; o > 0; o >>= 1) {
    if (threadIdx.x < o) red[threadIdx.x] += red[threadIdx.x + o];
    __syncthreads();
  }
  float inv = 1.0f / sqrtf(red[0] * (1.f / SDN) + 1e-6f);
  ushort_t* hr = Hflat + ((size_t)m << 11);
#pragma unroll
  for (int i = 0; i < 4; ++i) {
    int s = threadIdx.x + i * 256;
    hr[s] = f2bf_rne(v[i].x * inv);
    hr[SDN + s] = f2bf_rne(v[i].y * inv);
  }
}

// ---------------- simpson + RMS + MIMO + conj(phi) + tau/beta ----------------
__global__ __launch_bounds__(256) void final_kernel(
    const uint_t* __restrict__ V, const ushort_t* __restrict__ proj,
    const float* __restrict__ mimo, const float* __restrict__ tau,
    const float* __restrict__ beta, float* __restrict__ out) {
  int bid = blockIdx.x;
  int m = ((bid & 7) << 9) | (bid >> 3);
  int t = m & (LSEQ - 1);
  __shared__ float2 hl[SDN];
  __shared__ float red[256];
  float sum = 0.f;
#pragma unroll
  for (int i = 0; i < 4; ++i) {
    int s = threadIdx.x + i * 256;
    float2 v0 = upk2(V[(size_t)m * SDN + s]);
    float2 v1 = make_float2(0.f, 0.f), v2 = make_float2(0.f, 0.f);
    if (t >= 1) v1 = upk2(V[(size_t)(m - 1) * SDN + s]);
    if (t >= 2) v2 = upk2(V[(size_t)(m - 2) * SDN + s]);
    float2 h = make_float2((v0.x + 4.f * v1.x + v2.x) * (1.f / 6.f),
                           (v0.y + 4.f * v1.y + v2.y) * (1.f / 6.f));
    hl[s] = h;
    sum += h.x * h.x + h.y * h.y;
  }
  red[threadIdx.x] = sum;
  __syncthreads();
  for (int o = 128; o > 0; o >>= 1) {
    if (threadIdx.x < o) red[threadIdx.x] += red[threadIdx.x + o];
    __syncthreads();
  }
  float inv = 1.0f / sqrtf(red[0] * (1.f / SDN) + 1e-6f);
  float tv = tau[0], bv = beta[0];
  const ushort_t* pp = proj + ((size_t)m << 13) + 2048;
#pragma unroll
  for (int i = 0; i < 4; ++i) {
    int s = threadIdx.x + i * 256;
    int g = s >> 3, q = s & 7;
    const float* wp = mimo + (size_t)g * 64 + q;
    float hr = 0.f, hi = 0.f;
#pragma unroll
    for (int p = 0; p < 8; ++p) {
      float wv = wp[p * 8];
      float2 hp = hl[(g << 3) + p];
      hr = fmaf(hp.x, wv, hr);
      hi = fmaf(hp.y, wv, hi);
    }
    hr *= inv; hi *= inv;
    float o1 = hr * bf2f(pp[s]) + hi * bf2f(pp[SDN + s]);
    out[(size_t)m * SDN + s] = tv * o1 + bv;
  }
}

extern "C" void kernel_launch(void* const* d_in, const int* in_sizes, int n_in,
                              void* d_out, int out_size, void* d_ws, size_t ws_size,
                              hipStream_t stream) {
  const float* x      = (const float*)d_in[0];
  const float* z_prev = (const float*)d_in[1];
  const float* W_psi  = (const float*)d_in[2];
  const float* b_psi  = (const float*)d_in[3];
  const float* W_phi  = (const float*)d_in[4];
  const float* b_phi  = (const float*)d_in[5];
  const float* W_gate = (const float*)d_in[6];
  const float* b_gate = (const float*)d_in[7];
  const float* s_gain = (const float*)d_in[8];
  const float* omega  = (const float*)d_in[9];
  const float* log_g  = (const float*)d_in[10];
  const float* dt     = (const float*)d_in[11];
  const float* W_bs   = (const float*)d_in[12];
  const float* b_bs   = (const float*)d_in[13];
  const float* W_ps   = (const float*)d_in[14];
  const float* b_ps   = (const float*)d_in[15];
  const float* W_btx  = (const float*)d_in[16];
  const float* b_btx  = (const float*)d_in[17];
  const float* W_bth  = (const float*)d_in[18];
  const float* b_bth  = (const float*)d_in[19];
  const float* W_ptx  = (const float*)d_in[20];
  const float* b_ptx  = (const float*)d_in[21];
  const float* mimo_w = (const float*)d_in[22];
  const float* tau    = (const float*)d_in[23];
  const float* beta   = (const float*)d_in[24];
  float* out = (float*)d_out;

  float* ws = (float*)d_ws;
  const size_t M1 = 1 << 20;
  // ---- workspace layout, float units ----
  // [0,16M)   proj   : 32M bf16 = [4096][8192]
  // [16M,20M) U/V    : 4M uint (packed 2x bf16), scan in-place
  // [24M,26M) xb     : 4M bf16
  // [26M,30M) wcat   : 8M bf16 [8192][1024]; P0/P1 alias after fused GEMM
  // [30M,31M) wbthb  : 2M bf16 [1024][2048]
  // [31M,35M) hflatB : 8M bf16 [4096][2048]
  // [35M,..)  bcat(8192) gate(4096) ac(2048) Ac(2048) carry(256K) prefix(256K)
  ushort_t* proj   = (ushort_t*)ws;
  uint_t*   U      = (uint_t*)(ws + 16 * M1);
  uint_t*   V      = U;
  ushort_t* xb     = (ushort_t*)(ws + 24 * M1);
  ushort_t* wcat   = (ushort_t*)(ws + 26 * M1);
  ushort_t* P0     = wcat;
  ushort_t* P1     = wcat + 4u * 1024u * 1024u;
  ushort_t* wbthb  = (ushort_t*)(ws + 30 * M1);
  ushort_t* hflatB = (ushort_t*)(ws + 31 * M1);
  float*    bcat   = ws + 35 * M1;
  float*    gate   = bcat + 8192;
  float2*   ac     = (float2*)(gate + 4096);
  float2*   Ac     = ac + 1024;
  float2*   carry  = Ac + 1024;                 // 131072 float2
  float2*   prefix = carry + 131072;            // 131072 float2
  (void)ws_size; (void)in_sizes; (void)n_in; (void)out_size;

  dim3 blk(256);
  dim3 sgrid(SDN / 256, NCHUNK, BATCHN);

  // one prep launch: x-convert+gate, weight converts, bias concat, coef
  prep_kernel<<<dim3(14372), blk, 0, stream>>>(
      x, z_prev, W_psi, W_phi, W_bs, W_ps, W_btx, W_ptx, W_bth,
      b_psi, b_phi, b_bs, b_ps, b_btx, b_ptx,
      W_gate, b_gate, s_gain, omega, log_g, dt,
      xb, wcat, wbthb, bcat, gate, ac, Ac);

  // fused projection GEMM (R4-verified)
  gemm_bf16<0><<<dim3(2048), blk, 0, stream>>>(xb, wcat, bcat, proj);

  // U_scout, scan 1
  u_scout<<<dim3(BLROWS * SDN / 512), blk, 0, stream>>>(gate, proj, U);
  scan_stage1<<<sgrid, blk, 0, stream>>>(U, ac, carry);
  scan_stage2<<<dim3(SDN / 256, 1, BATCHN), blk, 0, stream>>>(carry, Ac, prefix);
  scan_stage3<<<sgrid, blk, 0, stream>>>(U, ac, prefix, V);

  // H_flat, split-K bth GEMM
  hflat_kernel<<<dim3(BLROWS), blk, 0, stream>>>(V, hflatB);
  gemm_bf16<1><<<dim3(8, 32, 2), blk, 0, stream>>>(hflatB, wbthb, bcat, P0);

  // U_true, scan 2
  u_true<<<dim3(BLROWS * SDN / 512), blk, 0, stream>>>(gate, proj, P0, P1, b_bth, U);
  scan_stage1<<<sgrid, blk, 0, stream>>>(U, ac, carry);
  scan_stage2<<<dim3(SDN / 256, 1, BATCHN), blk, 0, stream>>>(carry, Ac, prefix);
  scan_stage3<<<sgrid, blk, 0, stream>>>(U, ac, prefix, V);

  // fused epilogue
  final_kernel<<<dim3(BLROWS), blk, 0, stream>>>(V, proj, mimo_w, tau, beta, out);
}

// Round 10
// 202.454 us; speedup vs baseline: 1.5151x; 1.0342x over previous
//
#include <hip/hip_runtime.h>
#include <math.h>

#define DIMX   1024
#define SDN    1024
#define BATCHN 2
#define LSEQ   2048
#define BLROWS (BATCHN*LSEQ)
#define NCHUNK 128
#define LCHUNK (LSEQ/NCHUNK)
#define PI_F   3.14159265358979f

typedef unsigned short ushort_t;
typedef unsigned int uint_t;
typedef __bf16 bf16_t;
typedef bf16_t bf16x8 __attribute__((ext_vector_type(8)));
typedef float f32x4 __attribute__((ext_vector_type(4)));

__device__ __forceinline__ ushort_t f2bf_rne(float f) {
  unsigned u = __float_as_uint(f);
  u = u + 0x7fffu + ((u >> 16) & 1u);
  return (ushort_t)(u >> 16);
}

__device__ __forceinline__ float bf2f(ushort_t u) {
  return __uint_as_float(((unsigned)u) << 16);
}

__device__ __forceinline__ uint_t pk2(float2 v) {
  return (uint_t)f2bf_rne(v.x) | ((uint_t)f2bf_rne(v.y) << 16);
}
__device__ __forceinline__ float2 upk2(uint_t u) {
  return make_float2(__uint_as_float(u << 16), __uint_as_float(u & 0xffff0000u));
}

__device__ __forceinline__ float2 cfma2(float2 a, float2 v, float2 u) {
  float re = fmaf(a.x, v.x, fmaf(-a.y, v.y, u.x));
  float im = fmaf(a.x, v.y, fmaf(a.y, v.x, u.y));
  return make_float2(re, im);
}
__device__ __forceinline__ float2 cmul2(float2 a, float2 b) {
  return make_float2(a.x * b.x - a.y * b.y, a.x * b.y + a.y * b.x);
}

// fast softplus / tanh (u-kernels; ~1e-6 rel err, absorbed by bf16 noise)
__device__ __forceinline__ float fast_softplus(float x) {
  return x > 15.f ? x : __logf(1.f + __expf(x));
}
__device__ __forceinline__ float fast_tanh(float x) {
  float xc = fminf(fmaxf(x, -9.f), 9.f);
  float t = __expf(2.f * xc);
  return (t - 1.f) * __builtin_amdgcn_rcpf(t + 1.f);
}

__device__ __forceinline__ void gload_lds16(const ushort_t* g, ushort_t* l) {
  __builtin_amdgcn_global_load_lds(
      (const __attribute__((address_space(1))) void*)g,
      (__attribute__((address_space(3))) void*)l, 16, 0, 0);
}

// ---------------- mega prep kernel (R9-verified) ----------------
__global__ __launch_bounds__(256) void prep_kernel(
    const float* __restrict__ x, const float* __restrict__ z_prev,
    const float* __restrict__ Wpsi, const float* __restrict__ Wphi,
    const float* __restrict__ Wbs, const float* __restrict__ Wps,
    const float* __restrict__ Wbtx, const float* __restrict__ Wptx,
    const float* __restrict__ Wbth,
    const float* __restrict__ b_psi, const float* __restrict__ b_phi,
    const float* __restrict__ b_bs, const float* __restrict__ b_ps,
    const float* __restrict__ b_btx, const float* __restrict__ b_ptx,
    const float* __restrict__ Wg, const float* __restrict__ bg,
    const float* __restrict__ sg,
    const float* __restrict__ omega, const float* __restrict__ log_gamma,
    const float* __restrict__ dt,
    ushort_t* __restrict__ xb, ushort_t* __restrict__ wcat,
    ushort_t* __restrict__ wbthb, float* __restrict__ bcat,
    float* __restrict__ gate, float2* __restrict__ a_out,
    float2* __restrict__ A_out) {
  int b = blockIdx.x;
  int tid = threadIdx.x;
  if (b < 4096) {
    int i = tid * 4;
    const float* xp = x + (size_t)b * DIMX;
    const float* zp = z_prev + (size_t)b * DIMX;
    float4 xv = *(const float4*)(xp + i);
    float4 zv = *(const float4*)(zp + i);
    float4 wv = *(const float4*)(Wg + i);
    ushort4 o;
    o.x = f2bf_rne(xv.x); o.y = f2bf_rne(xv.y);
    o.z = f2bf_rne(xv.z); o.w = f2bf_rne(xv.w);
    *(ushort4*)(xb + (size_t)b * DIMX + i) = o;
    float dot = xv.x * wv.x + xv.y * wv.y + xv.z * wv.z + xv.w * wv.w;
    float sur = fabsf(xv.x - zv.x) + fabsf(xv.y - zv.y) +
                fabsf(xv.z - zv.z) + fabsf(xv.w - zv.w);
    __shared__ float sdot[256], ssur[256];
    sdot[tid] = dot; ssur[tid] = sur;
    __syncthreads();
    for (int o_ = 128; o_ > 0; o_ >>= 1) {
      if (tid < o_) { sdot[tid] += sdot[tid + o_]; ssur[tid] += ssur[tid + o_]; }
      __syncthreads();
    }
    if (tid == 0) {
      float gs = 1.f / (1.f + expf(-(sdot[0] + bg[0])));
      gate[b] = gs * (1.f + tanhf(sg[0]) * (ssur[0] * (1.f / DIMX)));
    }
    return;
  }
  b -= 4096;
  if (b < 10240) {  // weight conversion: 8192 wcat + 2048 wbth
    const float* src; ushort_t* dst; int off;
    if (b < 2048)       { src = Wpsi; dst = wcat;             off = b; }
    else if (b < 4096)  { src = Wphi; dst = wcat + 2097152u;  off = b - 2048; }
    else if (b < 5120)  { src = Wbs;  dst = wcat + 4194304u;  off = b - 4096; }
    else if (b < 6144)  { src = Wps;  dst = wcat + 5242880u;  off = b - 5120; }
    else if (b < 7168)  { src = Wbtx; dst = wcat + 6291456u;  off = b - 6144; }
    else if (b < 8192)  { src = Wptx; dst = wcat + 7340032u;  off = b - 7168; }
    else                { src = Wbth; dst = wbthb;            off = b - 8192; }
    int i = (off * 256 + tid) * 4;
    float4 v = *(const float4*)(src + i);
    ushort4 o;
    o.x = f2bf_rne(v.x); o.y = f2bf_rne(v.y);
    o.z = f2bf_rne(v.z); o.w = f2bf_rne(v.w);
    *(ushort4*)(dst + i) = o;
    return;
  }
  b -= 10240;  // b in [0,36)
  if (b < 32) {
    int n = b * 256 + tid;
    float v;
    if (n < 2048) v = b_psi[n];
    else if (n < 4096) v = b_phi[n - 2048];
    else if (n < 5120) v = b_bs[n - 4096];
    else if (n < 6144) v = b_ps[n - 5120];
    else if (n < 7168) v = b_btx[n - 6144];
    else v = b_ptx[n - 7168];
    bcat[n] = v;
    return;
  }
  int s = (b - 32) * 256 + tid;
  double dtv = (double)dt[0];
  double dte = dtv > 20.0 ? dtv : log1p(exp(dtv));
  double gam = 0.0;
  if (s < SDN - SDN / 4) {  // band0 = [768,1023] (freqs strictly decreasing)
    double lg = (double)log_gamma[s];
    gam = lg > 20.0 ? lg : log1p(exp(lg));
  }
  double th = (double)omega[s] * dte;
  double r  = exp(-gam * dte);
  a_out[s] = make_float2((float)(r * cos(th)), (float)(r * sin(th)));
  double thl = th * (double)LCHUNK;
  double rl  = exp(-gam * dte * (double)LCHUNK);
  A_out[s] = make_float2((float)(rl * cos(thl)), (float)(rl * sin(thl)));
}

// ---------------- bf16 MFMA GEMM (R4-verified) ----------------
template<int MODE>
__global__ __launch_bounds__(256, 2) void gemm_bf16(
    const ushort_t* __restrict__ Xb, const ushort_t* __restrict__ Wb,
    const float* __restrict__ bias, ushort_t* __restrict__ Cb) {
  __shared__ ushort_t As[2][4096];
  __shared__ ushort_t Bs[2][4096];
  const int tid = threadIdx.x;
  const int w = tid >> 6, l = tid & 63;
  int bm, bn, ldx, ldw;
  const ushort_t *Xp, *Wp;
  if (MODE == 0) {
    int b = blockIdx.x;
    int xcd = b & 7, idx = b >> 3;
    int tx = ((xcd & 3) << 4) + (idx & 15);
    int ty = ((xcd >> 2) << 4) + (idx >> 4);
    bm = ty << 7; bn = tx << 7;
    ldx = 1024; ldw = 1024;
    Xp = Xb; Wp = Wb;
  } else {
    bm = blockIdx.y << 7; bn = blockIdx.x << 7;
    ldx = 2048; ldw = 2048;
    Xp = Xb + blockIdx.z * 1024;
    Wp = Wb + blockIdx.z * 1024;
  }
  const int wr = w >> 1, wc = w & 1;

  const int srow = tid >> 2;
  const int c8 = (((tid & 3) - (tid >> 3)) & 3) << 3;
  const ushort_t* ga0 = Xp + (size_t)(bm + srow) * ldx + c8;
  const ushort_t* ga1 = Xp + (size_t)(bm + 64 + srow) * ldx + c8;
  const ushort_t* gb0 = Wp + (size_t)(bn + srow) * ldw + c8;
  const ushort_t* gb1 = Wp + (size_t)(bn + 64 + srow) * ldw + c8;

  f32x4 acc[4][4] = {};
  const int nk = 32;

#define STAGE(buf, kt)                                   \
  do {                                                   \
    gload_lds16(ga0 + (kt), &As[buf][w * 512]);          \
    gload_lds16(ga1 + (kt), &As[buf][2048 + w * 512]);   \
    gload_lds16(gb0 + (kt), &Bs[buf][w * 512]);          \
    gload_lds16(gb1 + (kt), &Bs[buf][2048 + w * 512]);   \
  } while (0)

  STAGE(0, 0);
  __syncthreads();

  const int rl = l & 15, kh = l >> 4;
  const int chunkp = (kh + (rl >> 1)) & 3;
  for (int kt = 0; kt < nk; ++kt) {
    int cur = kt & 1;
    if (kt + 1 < nk) STAGE(cur ^ 1, (kt + 1) * 32);
    const uint4* Af = (const uint4*)As[cur];
    const uint4* Bf = (const uint4*)Bs[cur];
    bf16x8 a[4], b[4];
#pragma unroll
    for (int i = 0; i < 4; ++i)
      a[i] = __builtin_bit_cast(bf16x8, Af[(wr * 64 + i * 16 + rl) * 4 + chunkp]);
#pragma unroll
    for (int j = 0; j < 4; ++j)
      b[j] = __builtin_bit_cast(bf16x8, Bf[(wc * 64 + j * 16 + rl) * 4 + chunkp]);
#pragma unroll
    for (int i = 0; i < 4; ++i)
#pragma unroll
      for (int j = 0; j < 4; ++j)
        acc[i][j] = __builtin_amdgcn_mfma_f32_16x16x32_bf16(a[i], b[j], acc[i][j], 0, 0, 0);
    __syncthreads();
  }
#undef STAGE

#pragma unroll
  for (int i = 0; i < 4; ++i) {
    int mrow = bm + wr * 64 + i * 16 + (l >> 4) * 4;
#pragma unroll
    for (int j = 0; j < 4; ++j) {
      int ncol = bn + wc * 64 + j * 16 + (l & 15);
      if (MODE == 0) {
        float bv = bias[ncol];
#pragma unroll
        for (int r = 0; r < 4; ++r)
          Cb[(size_t)(mrow + r) * 8192 + ncol] = f2bf_rne(acc[i][j][r] + bv);
      } else {
        ushort_t* P = Cb + (size_t)blockIdx.z * (4096u * 1024u);
#pragma unroll
        for (int r = 0; r < 4; ++r)
          P[(size_t)(mrow + r) * 1024 + ncol] = f2bf_rne(acc[i][j][r]);
      }
    }
  }
}

// proj row layout (8192 bf16): psi_re | psi_im | phi_re | phi_im | bs | ps | btx | ptx

// ---------------- U_scout (2 elems/thread, fast-math; R9-verified) ----------------
__global__ __launch_bounds__(256) void u_scout(
    const float* __restrict__ gate, const ushort_t* __restrict__ proj,
    uint_t* __restrict__ U) {
  int idx2 = blockIdx.x * 256 + threadIdx.x;
  int m = idx2 >> 9, sp = (idx2 & 511) << 1;
  const ushort_t* pr = proj + ((size_t)m << 13);
  float g = gate[m];
  uint_t bsu = *(const uint_t*)(pr + 4096 + sp);
  uint_t psu = *(const uint_t*)(pr + 5120 + sp);
  uint_t pre = *(const uint_t*)(pr + sp);
  uint_t pim = *(const uint_t*)(pr + 1024 + sp);
  uint_t o[2];
#pragma unroll
  for (int e = 0; e < 2; ++e) {
    float bv = fast_softplus(bf2f((ushort_t)(e ? (bsu >> 16) : (bsu & 0xffff))));
    float ph = PI_F * fast_tanh(bf2f((ushort_t)(e ? (psu >> 16) : (psu & 0xffff))));
    float sph, cph;
    __sincosf(ph, &sph, &cph);
    float br = bv * cph, bi = bv * sph;
    float prf = bf2f((ushort_t)(e ? (pre >> 16) : (pre & 0xffff)));
    float pif = bf2f((ushort_t)(e ? (pim >> 16) : (pim & 0xffff)));
    o[e] = pk2(make_float2(g * (br * prf - bi * pif), g * (br * pif + bi * prf)));
  }
  *(uint2*)(U + ((size_t)m << 10) + sp) = make_uint2(o[0], o[1]);
}

// ---------------- U_true (2 elems/thread, fast-math; R9-verified) ----------------
__global__ __launch_bounds__(256) void u_true(
    const float* __restrict__ gate, const ushort_t* __restrict__ proj,
    const ushort_t* __restrict__ P0, const ushort_t* __restrict__ P1,
    const float* __restrict__ b_bth, uint_t* __restrict__ U) {
  int idx2 = blockIdx.x * 256 + threadIdx.x;
  int m = idx2 >> 9, sp = (idx2 & 511) << 1;
  const ushort_t* pr = proj + ((size_t)m << 13);
  float g = gate[m];
  size_t base = ((size_t)m << 10) + sp;
  uint_t btu = *(const uint_t*)(pr + 6144 + sp);
  uint_t ptu = *(const uint_t*)(pr + 7168 + sp);
  uint_t p0u = *(const uint_t*)(P0 + base);
  uint_t p1u = *(const uint_t*)(P1 + base);
  float2 bb = *(const float2*)(b_bth + sp);
  uint_t pre = *(const uint_t*)(pr + sp);
  uint_t pim = *(const uint_t*)(pr + 1024 + sp);
  uint_t o[2];
#pragma unroll
  for (int e = 0; e < 2; ++e) {
    float blv = bf2f((ushort_t)(e ? (btu >> 16) : (btu & 0xffff)))
              + bf2f((ushort_t)(e ? (p0u >> 16) : (p0u & 0xffff)))
              + bf2f((ushort_t)(e ? (p1u >> 16) : (p1u & 0xffff)))
              + (e ? bb.y : bb.x);
    float bv = fast_softplus(blv);
    float ph = PI_F * fast_tanh(bf2f((ushort_t)(e ? (ptu >> 16) : (ptu & 0xffff))));
    float sph, cph;
    __sincosf(ph, &sph, &cph);
    float br = bv * cph, bi = bv * sph;
    float prf = bf2f((ushort_t)(e ? (pre >> 16) : (pre & 0xffff)));
    float pif = bf2f((ushort_t)(e ? (pim >> 16) : (pim & 0xffff)));
    o[e] = pk2(make_float2(g * (br * prf - bi * pif), g * (br * pif + bi * prf)));
  }
  *(uint2*)(U + base) = make_uint2(o[0], o[1]);
}

// ---------------- chunked parallel scan on packed-bf16 U/V ----------------
__global__ __launch_bounds__(256) void scan_stage1(
    const uint_t* __restrict__ U, const float2* __restrict__ a,
    float2* __restrict__ carry) {
  int s = blockIdx.x * 256 + threadIdx.x;
  int c = blockIdx.y, b = blockIdx.z;
  float2 av = a[s];
  float2 V = make_float2(0.f, 0.f);
  const uint_t* Up = U + (size_t)(b * LSEQ + c * LCHUNK) * SDN + s;
#pragma unroll 8
  for (int t = 0; t < LCHUNK; ++t)
    V = cfma2(av, V, upk2(Up[(size_t)t * SDN]));
  carry[(size_t)(b * NCHUNK + c) * SDN + s] = V;
}

// wave-parallel prefix combine: one wave per (s,b) row, 2 chunks/lane,
// Hillis-Steele over 64 lane-pairs (multiplier uniform per s -> power by squaring).
__global__ __launch_bounds__(256) void scan_stage2(
    const float2* __restrict__ carry, const float2* __restrict__ Ac,
    float2* __restrict__ prefix) {
  int tid = threadIdx.x;
  int lane = tid & 63;
  int s = blockIdx.x * 4 + (tid >> 6);
  int b = blockIdx.z;
  float2 Av = Ac[s];
  size_t base0 = (size_t)(b * NCHUNK + 2 * lane) * SDN + s;
  float2 c0 = carry[base0];
  float2 c1 = carry[base0 + SDN];
  // pair-inclusive value: T over chunks {2l, 2l+1}
  float2 x = cfma2(Av, c0, c1);
  float2 M = cmul2(Av, Av);  // pair multiplier Av^2
#pragma unroll
  for (int sh = 1; sh < 64; sh <<= 1) {
    float2 y;
    y.x = __shfl_up(x.x, sh, 64);
    y.y = __shfl_up(x.y, sh, 64);
    if (lane >= sh) x = cfma2(M, y, x);
    M = cmul2(M, M);
  }
  // x = inclusive T through chunk 2*lane+1; prefix[c] = T_{c-1}
  float2 p0;
  p0.x = __shfl_up(x.x, 1, 64);
  p0.y = __shfl_up(x.y, 1, 64);
  if (lane == 0) p0 = make_float2(0.f, 0.f);
  float2 p1 = cfma2(Av, p0, c0);
  prefix[base0] = p0;
  prefix[base0 + SDN] = p1;
}

// in-place: Vout aliases U (read-then-write per element)
__global__ __launch_bounds__(256) void scan_stage3(
    const uint_t* __restrict__ U, const float2* __restrict__ a,
    const float2* __restrict__ prefix, uint_t* __restrict__ Vout) {
  int s = blockIdx.x * 256 + threadIdx.x;
  int c = blockIdx.y, b = blockIdx.z;
  float2 av = a[s];
  float2 V = prefix[(size_t)(b * NCHUNK + c) * SDN + s];
  size_t base = (size_t)(b * LSEQ + c * LCHUNK) * SDN + s;
#pragma unroll 8
  for (int t = 0; t < LCHUNK; ++t) {
    V = cfma2(av, V, upk2(U[base + (size_t)t * SDN]));
    Vout[base + (size_t)t * SDN] = pk2(V);
  }
}

// ---------------- H_flat (bf16) from packed V ----------------
__global__ __launch_bounds__(256) void hflat_kernel(
    const uint_t* __restrict__ V, ushort_t* __restrict__ Hflat) {
  int m = blockIdx.x;
  int t = m & (LSEQ - 1);
  float2 v[4];
  float sum = 0.f;
#pragma unroll
  for (int i = 0; i < 4; ++i) {
    int s = threadIdx.x + i * 256;
    float2 vv = make_float2(0.f, 0.f);
    if (t > 0) vv = upk2(V[(size_t)(m - 1) * SDN + s]);
    v[i] = vv;
    sum += vv.x * vv.x + vv.y * vv.y;
  }
  __shared__ float red[256];
  red[threadIdx.x] = sum;
  __syncthreads();
  for (int o = 128; o > 0; o >>= 1) {
    if (threadIdx.x < o) red[threadIdx.x] += red[threadIdx.x + o];
    __syncthreads();
  }
  float inv = 1.0f / sqrtf(red[0] * (1.f / SDN) + 1e-6f);
  ushort_t* hr = Hflat + ((size_t)m << 11);
#pragma unroll
  for (int i = 0; i < 4; ++i) {
    int s = threadIdx.x + i * 256;
    hr[s] = f2bf_rne(v[i].x * inv);
    hr[SDN + s] = f2bf_rne(v[i].y * inv);
  }
}

// ---------------- simpson + RMS + MIMO + conj(phi) + tau/beta ----------------
__global__ __launch_bounds__(256) void final_kernel(
    const uint_t* __restrict__ V, const ushort_t* __restrict__ proj,
    const float* __restrict__ mimo, const float* __restrict__ tau,
    const float* __restrict__ beta, float* __restrict__ out) {
  int bid = blockIdx.x;
  int m = ((bid & 7) << 9) | (bid >> 3);
  int t = m & (LSEQ - 1);
  __shared__ float2 hl[SDN];
  __shared__ float red[256];
  float sum = 0.f;
#pragma unroll
  for (int i = 0; i < 4; ++i) {
    int s = threadIdx.x + i * 256;
    float2 v0 = upk2(V[(size_t)m * SDN + s]);
    float2 v1 = make_float2(0.f, 0.f), v2 = make_float2(0.f, 0.f);
    if (t >= 1) v1 = upk2(V[(size_t)(m - 1) * SDN + s]);
    if (t >= 2) v2 = upk2(V[(size_t)(m - 2) * SDN + s]);
    float2 h = make_float2((v0.x + 4.f * v1.x + v2.x) * (1.f / 6.f),
                           (v0.y + 4.f * v1.y + v2.y) * (1.f / 6.f));
    hl[s] = h;
    sum += h.x * h.x + h.y * h.y;
  }
  red[threadIdx.x] = sum;
  __syncthreads();
  for (int o = 128; o > 0; o >>= 1) {
    if (threadIdx.x < o) red[threadIdx.x] += red[threadIdx.x + o];
    __syncthreads();
  }
  float inv = 1.0f / sqrtf(red[0] * (1.f / SDN) + 1e-6f);
  float tv = tau[0], bv = beta[0];
  const ushort_t* pp = proj + ((size_t)m << 13) + 2048;
#pragma unroll
  for (int i = 0; i < 4; ++i) {
    int s = threadIdx.x + i * 256;
    int g = s >> 3, q = s & 7;
    const float* wp = mimo + (size_t)g * 64 + q;
    float hr = 0.f, hi = 0.f;
#pragma unroll
    for (int p = 0; p < 8; ++p) {
      float wv = wp[p * 8];
      float2 hp = hl[(g << 3) + p];
      hr = fmaf(hp.x, wv, hr);
      hi = fmaf(hp.y, wv, hi);
    }
    hr *= inv; hi *= inv;
    float o1 = hr * bf2f(pp[s]) + hi * bf2f(pp[SDN + s]);
    out[(size_t)m * SDN + s] = tv * o1 + bv;
  }
}

extern "C" void kernel_launch(void* const* d_in, const int* in_sizes, int n_in,
                              void* d_out, int out_size, void* d_ws, size_t ws_size,
                              hipStream_t stream) {
  const float* x      = (const float*)d_in[0];
  const float* z_prev = (const float*)d_in[1];
  const float* W_psi  = (const float*)d_in[2];
  const float* b_psi  = (const float*)d_in[3];
  const float* W_phi  = (const float*)d_in[4];
  const float* b_phi  = (const float*)d_in[5];
  const float* W_gate = (const float*)d_in[6];
  const float* b_gate = (const float*)d_in[7];
  const float* s_gain = (const float*)d_in[8];
  const float* omega  = (const float*)d_in[9];
  const float* log_g  = (const float*)d_in[10];
  const float* dt     = (const float*)d_in[11];
  const float* W_bs   = (const float*)d_in[12];
  const float* b_bs   = (const float*)d_in[13];
  const float* W_ps   = (const float*)d_in[14];
  const float* b_ps   = (const float*)d_in[15];
  const float* W_btx  = (const float*)d_in[16];
  const float* b_btx  = (const float*)d_in[17];
  const float* W_bth  = (const float*)d_in[18];
  const float* b_bth  = (const float*)d_in[19];
  const float* W_ptx  = (const float*)d_in[20];
  const float* b_ptx  = (const float*)d_in[21];
  const float* mimo_w = (const float*)d_in[22];
  const float* tau    = (const float*)d_in[23];
  const float* beta   = (const float*)d_in[24];
  float* out = (float*)d_out;

  float* ws = (float*)d_ws;
  const size_t M1 = 1 << 20;
  // ---- workspace layout, float units ----
  // [0,16M)   proj   : 32M bf16 = [4096][8192]
  // [16M,20M) U/V    : 4M uint (packed 2x bf16), scan in-place
  // [24M,26M) xb     : 4M bf16
  // [26M,30M) wcat   : 8M bf16 [8192][1024]; P0/P1 alias after fused GEMM
  // [30M,31M) wbthb  : 2M bf16 [1024][2048]
  // [31M,35M) hflatB : 8M bf16 [4096][2048]
  // [35M,..)  bcat(8192) gate(4096) ac(2048) Ac(2048)
  //           carry(NCHUNK*SDN*BATCHN=256K float2) prefix(256K float2)
  ushort_t* proj   = (ushort_t*)ws;
  uint_t*   U      = (uint_t*)(ws + 16 * M1);
  uint_t*   V      = U;
  ushort_t* xb     = (ushort_t*)(ws + 24 * M1);
  ushort_t* wcat   = (ushort_t*)(ws + 26 * M1);
  ushort_t* P0     = wcat;
  ushort_t* P1     = wcat + 4u * 1024u * 1024u;
  ushort_t* wbthb  = (ushort_t*)(ws + 30 * M1);
  ushort_t* hflatB = (ushort_t*)(ws + 31 * M1);
  float*    bcat   = ws + 35 * M1;
  float*    gate   = bcat + 8192;
  float2*   ac     = (float2*)(gate + 4096);
  float2*   Ac     = ac + 1024;
  float2*   carry  = Ac + 1024;                 // 262144 float2
  float2*   prefix = carry + 262144;            // 262144 float2
  (void)ws_size; (void)in_sizes; (void)n_in; (void)out_size;

  dim3 blk(256);
  dim3 sgrid(SDN / 256, NCHUNK, BATCHN);
  dim3 s2grid(SDN / 4, 1, BATCHN);

  // one prep launch: x-convert+gate, weight converts, bias concat, coef
  prep_kernel<<<dim3(14372), blk, 0, stream>>>(
      x, z_prev, W_psi, W_phi, W_bs, W_ps, W_btx, W_ptx, W_bth,
      b_psi, b_phi, b_bs, b_ps, b_btx, b_ptx,
      W_gate, b_gate, s_gain, omega, log_g, dt,
      xb, wcat, wbthb, bcat, gate, ac, Ac);

  // fused projection GEMM (R4-verified)
  gemm_bf16<0><<<dim3(2048), blk, 0, stream>>>(xb, wcat, bcat, proj);

  // U_scout, scan 1
  u_scout<<<dim3(BLROWS * SDN / 512), blk, 0, stream>>>(gate, proj, U);
  scan_stage1<<<sgrid, blk, 0, stream>>>(U, ac, carry);
  scan_stage2<<<s2grid, blk, 0, stream>>>(carry, Ac, prefix);
  scan_stage3<<<sgrid, blk, 0, stream>>>(U, ac, prefix, V);

  // H_flat, split-K bth GEMM
  hflat_kernel<<<dim3(BLROWS), blk, 0, stream>>>(V, hflatB);
  gemm_bf16<1><<<dim3(8, 32, 2), blk, 0, stream>>>(hflatB, wbthb, bcat, P0);

  // U_true, scan 2
  u_true<<<dim3(BLROWS * SDN / 512), blk, 0, stream>>>(gate, proj, P0, P1, b_bth, U);
  scan_stage1<<<sgrid, blk, 0, stream>>>(U, ac, carry);
  scan_stage2<<<s2grid, blk, 0, stream>>>(carry, Ac, prefix);
  scan_stage3<<<sgrid, blk, 0, stream>>>(U, ac, prefix, V);

  // fused epilogue
  final_kernel<<<dim3(BLROWS), blk, 0, stream>>>(V, proj, mimo_w, tau, beta, out);
}